// Round 1
// baseline (560.289 us; speedup 1.0000x reference)
//
#include <hip/hip_runtime.h>
#include <hip/hip_bf16.h>

// Dims: B=256, Nv=196, Lt=32, Ci=768, Ct=512, H=12, D=64
// M1 = 50176 (=196*256), M2 = 8192 (=64*128), N = 768

typedef __attribute__((ext_vector_type(8))) short bf16x8;
typedef __attribute__((ext_vector_type(4))) float f32x4;

__device__ __forceinline__ float bf2f(unsigned short u) {
    return __uint_as_float(((unsigned int)u) << 16);
}
__device__ __forceinline__ unsigned short f2bf(float f) {
    unsigned int x = __float_as_uint(f);
    unsigned int r = (x + 0x7FFFu + ((x >> 16) & 1u)) >> 16;  // RNE
    return (unsigned short)r;
}

// async global->LDS, 16B/lane. LDS dest is wave-uniform base + lane*16.
#define GLOAD_LDS16(gp, lp)                                                    \
    __builtin_amdgcn_global_load_lds(                                          \
        (__attribute__((address_space(1))) void*)(gp),                         \
        (__attribute__((address_space(3))) void*)(lp), 16, 0, 0)

#define BAR()  __builtin_amdgcn_s_barrier()
#define LGKM0 asm volatile("s_waitcnt lgkmcnt(0)" ::: "memory")
#define VMC0  asm volatile("s_waitcnt vmcnt(0)" ::: "memory")
#define VMC4  asm volatile("s_waitcnt vmcnt(4)" ::: "memory")
#define VMC6  asm volatile("s_waitcnt vmcnt(6)" ::: "memory")

// ---------------- fp32 -> bf16 convert (vectorized) ----------------
__global__ void cvt_bf16_kernel(const float* __restrict__ in,
                                unsigned short* __restrict__ out, int n4) {
    int i = blockIdx.x * 256 + threadIdx.x;
    if (i >= n4) return;
    float4 v = ((const float4*)in)[i];
    ushort4 o;
    o.x = f2bf(v.x); o.y = f2bf(v.y); o.z = f2bf(v.z); o.w = f2bf(v.w);
    ((ushort4*)out)[i] = o;
}

// ---------------- W[K][N] -> Wt[N][K] transpose + bf16 ----------------
__global__ void transpose_cvt_kernel(const float* __restrict__ W,
                                     unsigned short* __restrict__ Wt,
                                     int K, int N) {
    __shared__ float tile[32][33];
    int n0 = blockIdx.x * 32, k0 = blockIdx.y * 32;
    int tx = threadIdx.x & 31, ty = threadIdx.x >> 5;  // 256 thr: ty 0..7
    #pragma unroll
    for (int r = ty; r < 32; r += 8)
        tile[r][tx] = W[(size_t)(k0 + r) * N + n0 + tx];
    __syncthreads();
    #pragma unroll
    for (int r = ty; r < 32; r += 8)
        Wt[(size_t)(n0 + r) * K + k0 + tx] = f2bf(tile[tx][r]);
}

// ---------------- 256x256 8-phase bf16 MFMA GEMM: C = A * Bt^T + bias ------
// T3+T4+T5 structure (learn_hip m201): BM=BN=256, BK=64, 8 waves (2Mx4N),
// 512 thr, double-buffered K-tiles, counted vmcnt(6) (never 0 in loop),
// raw s_barrier, setprio around each 16-MFMA quadrant.
// LDS layout = proven chunk-XOR scheme (row r's 16B chunk g stored at slot
// g^(r&7); global source pre-swizzled so global_load_lds writes linearly):
// fragment ds_read_b128 is conflict-free-min, staging is contiguous.
// Pipeline (per tile t, phases p0..p3):
//   reads:  p0: A-frags 0-3 (8) + B-frags 0-1 (4); p1: B 2-3 (4); p2: A 4-7 (8)
//   mfma:   p0 (Alo x Blo), p1 (Alo x Bhi), p2 (Ahi x Blo), p3 (Ahi x Bhi)
//   stages: p0: A1[t+1];  p2: B0[t+2];  p3: B1[t+2], A0[t+2], then vmcnt(6)
// Region safety: every stage lands after the phase whose lgkmcnt(0) drained
// the last read of that region (asm "memory" fences pin cross-phase motion).
template<int KTOT, int GELU>
__global__ __launch_bounds__(512, 1)
void gemm256_kernel(const unsigned short* __restrict__ A,
                    const unsigned short* __restrict__ Bt,
                    const float* __restrict__ bias,
                    unsigned short* __restrict__ C) {
    constexpr int NT = KTOT / 64;      // K-tiles (12 or 8)
    constexpr int GS = 520;            // shorts per 8-row group (512 + 8 pad)
    constexpr int TSZ = 32 * GS;       // one 256x64 tile
    __shared__ unsigned short As[2 * TSZ];   // 66,560 B
    __shared__ unsigned short Bs[2 * TSZ];   // 66,560 B (total 133,120 <= 160K)
    const int tid = threadIdx.x;
    const int lane = tid & 63, wave = tid >> 6;   // 8 waves
    const int wm = wave >> 2, wn = wave & 3;      // 2 x 4 wave grid
    const int lr = lane & 15, quad = lane >> 4;
    const int s7 = lane & 7;
    const int rp = ((lr >> 3) * GS) + ((lane & 7) << 6);  // row part (shorts)

    // bijective XCD swizzle (m204): consecutive wg on one XCD share A-panels
    const int nwg = gridDim.x;
    const int qq = nwg >> 3, r8 = nwg & 7;
    const int xcd = blockIdx.x & 7, loc = blockIdx.x >> 3;
    const int wg = (xcd < r8 ? xcd * (qq + 1) : r8 * (qq + 1) + (xcd - r8) * qq) + loc;
    const int mt = wg / 3, nt = wg - mt * 3;   // nt fastest: A-panel L2 reuse x3
    const size_t m0 = (size_t)mt * 256;
    const int n0 = nt * 256;

    // staging: lane -> row (lane>>3) of an 8-row group, global chunk
    // (lane&7)^(lane>>3) so the linear LDS image holds chunk g at slot g^(r&7)
    const int swz = ((lane & 7) ^ (lane >> 3)) * 8;
    const unsigned short* gA = A + (m0 + (lane >> 3)) * (size_t)KTOT + swz;
    const unsigned short* gB = Bt + ((size_t)(n0 + (lane >> 3))) * KTOT + swz;

#define STG_A(b, t, h) do {                                                    \
    const int g0_ = (h) * 16 + wave * 2;                                       \
    GLOAD_LDS16(gA + (size_t)(g0_) * 8 * KTOT + (t) * 64,                      \
                As + (b) * TSZ + (g0_) * GS);                                  \
    GLOAD_LDS16(gA + (size_t)(g0_ + 1) * 8 * KTOT + (t) * 64,                  \
                As + (b) * TSZ + (g0_ + 1) * GS);                              \
} while (0)
#define STG_B(b, t, h) do {                                                    \
    const int g0_ = (h) * 16 + wave * 2;                                       \
    GLOAD_LDS16(gB + (size_t)(g0_) * 8 * KTOT + (t) * 64,                      \
                Bs + (b) * TSZ + (g0_) * GS);                                  \
    GLOAD_LDS16(gB + (size_t)(g0_ + 1) * 8 * KTOT + (t) * 64,                  \
                Bs + (b) * TSZ + (g0_ + 1) * GS);                              \
} while (0)

    f32x4 acc[8][4] = {};
    bf16x8 aR[4][2], bR[4][2];

#define LDA_FRAGS(ibase)                                                       \
    _Pragma("unroll")                                                          \
    for (int i = 0; i < 4; ++i)                                                \
        _Pragma("unroll")                                                      \
        for (int kk = 0; kk < 2; ++kk)                                         \
            aR[i][kk] = *(const bf16x8*)(pa + (wm * 16 + ((ibase) + i) * 2) * GS \
                         + rp + ((((kk * 4) + quad) ^ s7) << 3));

#define LDB_FRAGS(jbase)                                                       \
    _Pragma("unroll")                                                          \
    for (int j = 0; j < 2; ++j)                                                \
        _Pragma("unroll")                                                      \
        for (int kk = 0; kk < 2; ++kk)                                         \
            bR[(jbase) + j][kk] = *(const bf16x8*)(pb + (wn * 8 + ((jbase) + j) * 2) * GS \
                         + rp + ((((kk * 4) + quad) ^ s7) << 3));

#define MFMA_Q(I0, J0)                                                         \
    __builtin_amdgcn_s_setprio(1);                                             \
    _Pragma("unroll")                                                          \
    for (int i = 0; i < 4; ++i)                                                \
        _Pragma("unroll")                                                      \
        for (int j = 0; j < 2; ++j)                                            \
            _Pragma("unroll")                                                  \
            for (int kk = 0; kk < 2; ++kk)                                     \
                acc[(I0) + i][(J0) + j] = __builtin_amdgcn_mfma_f32_16x16x32_bf16( \
                    aR[i][kk], bR[(J0) + j][kk], acc[(I0) + i][(J0) + j], 0, 0, 0); \
    __builtin_amdgcn_s_setprio(0);

    // prologue: tile0 fully, then 3 half-tiles of tile1; vmcnt(6) -> tile0 in
    STG_B(0, 0, 0); STG_B(0, 0, 1); STG_A(0, 0, 0); STG_A(0, 0, 1);
    VMC4;
    STG_B(1, 1, 0); STG_B(1, 1, 1); STG_A(1, 1, 0);
    VMC6;
    BAR();

    for (int t = 0; t < NT - 1; ++t) {
        const int buf = t & 1;
        const unsigned short* pa = As + buf * TSZ;
        const unsigned short* pb = Bs + buf * TSZ;
        const bool last = (t == NT - 2);
        // ---- p0 ----
        LDA_FRAGS(0); LDB_FRAGS(0);
        STG_A(buf ^ 1, t + 1, 1);
        BAR(); LGKM0;
        MFMA_Q(0, 0);
        BAR();
        // ---- p1 ----
        LDB_FRAGS(2);
        BAR(); LGKM0;
        MFMA_Q(0, 2);
        BAR();
        // ---- p2 ----
        LDA_FRAGS(4);
        if (!last) { STG_B(buf, t + 2, 0); } else { VMC4; }
        BAR(); LGKM0;
        MFMA_Q(4, 0);
        BAR();
        // ---- p3 ----
        if (!last) { STG_B(buf, t + 2, 1); STG_A(buf, t + 2, 0); VMC6; }
        else { VMC0; }
        BAR(); LGKM0;
        MFMA_Q(4, 2);
        BAR();
    }
    {   // tail tile NT-1: all data resident, reads+MFMA only
        const unsigned short* pa = As + ((NT - 1) & 1) * TSZ;
        const unsigned short* pb = Bs + ((NT - 1) & 1) * TSZ;
        LDA_FRAGS(0); LDB_FRAGS(0); LDB_FRAGS(2);
        MFMA_Q(0, 0);
        MFMA_Q(0, 2);
        LDA_FRAGS(4);
        MFMA_Q(4, 0);
        MFMA_Q(4, 2);
    }

    // epilogue: C/D layout col=lane&15, row=quad*4+reg  [m89-verified]
    #pragma unroll
    for (int j = 0; j < 4; ++j) {
        int col = n0 + wn * 64 + j * 16 + lr;
        float bv = bias[col];
        #pragma unroll
        for (int i = 0; i < 8; ++i) {
            #pragma unroll
            for (int r2 = 0; r2 < 4; ++r2) {
                size_t row = m0 + wm * 128 + i * 16 + quad * 4 + r2;
                float x = acc[i][j][r2] + bv;
                if (GELU) x = x / (1.0f + __expf(-1.702f * x));  // quick_gelu
                C[row * 768 + col] = f2bf(x);
            }
        }
    }
#undef STG_A
#undef STG_B
#undef LDA_FRAGS
#undef LDB_FRAGS
#undef MFMA_Q
}

// ---------------- bf16 MFMA GEMM (m97 structure), kept for small K/V -------
template<int KTOT, int GELU, int MTILES>
__global__ __launch_bounds__(256, 2)
void gemm_bt_kernel(const unsigned short* __restrict__ A,
                    const unsigned short* __restrict__ Bt,
                    const float* __restrict__ bias,
                    unsigned short* __restrict__ C) {
    constexpr int GS = 520;  // 8-row group stride in shorts (512 + 8 pad)
    __shared__ unsigned short As[16 * GS];
    __shared__ unsigned short Bs[16 * GS];
    const int tid = threadIdx.x;
    const int lane = tid & 63, wave = tid >> 6;
    const int id = blockIdx.x;
    const int xcd = id & 7, local = id >> 3;
    const int nt = local % 6, mt = xcd * (MTILES / 8) + local / 6;
    const size_t m0 = (size_t)mt * 128;
    const int n0 = nt * 128;
    const int wm = (wave >> 1) * 64, wn = (wave & 1) * 64;
    const int lr = lane & 15, quad = lane >> 4;

    const int swz = ((lane & 7) ^ (lane >> 3)) * 8;
    const unsigned short* gA = A + (m0 + wave * 32 + (lane >> 3)) * KTOT + swz;
    const unsigned short* gB = Bt + ((size_t)n0 + wave * 32 + (lane >> 3)) * KTOT + swz;
    unsigned short* lA = As + (wave * 4) * GS;
    unsigned short* lB = Bs + (wave * 4) * GS;

    f32x4 acc[4][4] = {};

    for (int kt = 0; kt < KTOT; kt += 64) {
        #pragma unroll
        for (int i = 0; i < 4; ++i) {
            GLOAD_LDS16(gA + (size_t)i * 8 * KTOT + kt, lA + i * GS);
            GLOAD_LDS16(gB + (size_t)i * 8 * KTOT + kt, lB + i * GS);
        }
        __syncthreads();
        #pragma unroll
        for (int kk = 0; kk < 64; kk += 32) {
            bf16x8 fa[4], fb[4];
            #pragma unroll
            for (int i = 0; i < 4; ++i) {
                int r = wm + i * 16 + lr;
                int g = (kk >> 3) + quad;
                fa[i] = *(const bf16x8*)(As + (r >> 3) * GS + (r & 7) * 64 +
                                         ((g ^ (r & 7)) << 3));
            }
            #pragma unroll
            for (int j = 0; j < 4; ++j) {
                int r = wn + j * 16 + lr;
                int g = (kk >> 3) + quad;
                fb[j] = *(const bf16x8*)(Bs + (r >> 3) * GS + (r & 7) * 64 +
                                         ((g ^ (r & 7)) << 3));
            }
            #pragma unroll
            for (int i = 0; i < 4; ++i)
                #pragma unroll
                for (int j = 0; j < 4; ++j)
                    acc[i][j] = __builtin_amdgcn_mfma_f32_16x16x32_bf16(
                        fa[i], fb[j], acc[i][j], 0, 0, 0);
        }
        __syncthreads();
    }

    #pragma unroll
    for (int j = 0; j < 4; ++j) {
        int col = n0 + wn + j * 16 + lr;
        float bv = bias[col];
        #pragma unroll
        for (int i = 0; i < 4; ++i) {
            #pragma unroll
            for (int r = 0; r < 4; ++r) {
                size_t row = m0 + wm + i * 16 + quad * 4 + r;
                float x = acc[i][j][r] + bv;
                if (GELU) x = x / (1.0f + __expf(-1.702f * x));
                C[row * 768 + col] = f2bf(x);
            }
        }
    }
}

// ---------------- MFMA attention: one block per (b,h), 4 waves -------------
__global__ __launch_bounds__(256, 4)
void attn_mfma_kernel(const unsigned short* __restrict__ Q,
                      const unsigned short* __restrict__ Kb,
                      const unsigned short* __restrict__ Vb,
                      unsigned short* __restrict__ RF) {
    constexpr int KS = 72;  // Ks row stride
    constexpr int VS = 34;  // Vt row stride
    constexpr int PS = 40;  // P row stride
    constexpr int CS = 72;  // ctx row stride
    __shared__ unsigned short Ks[32 * KS];      // K rows  [l][d]
    __shared__ unsigned short Vt[64 * VS];      // V^T     [d][l]
    __shared__ unsigned short Pb[4][16 * PS];   // per-wave P  [m][l]
    __shared__ unsigned short Cb[4][16 * CS];   // per-wave ctx[m][d]
    const int tid = threadIdx.x;
    const int b = blockIdx.x / 12, h = blockIdx.x % 12;
    const int lane = tid & 63, wave = tid >> 6;
    const int lr = lane & 15, quad = lane >> 4;

    {   // stage K rows + V transposed (bf16, one-time)
        int l = tid >> 3, d8 = (tid & 7) * 8;
        size_t base = ((size_t)b * 32 + l) * 768 + (size_t)h * 64 + d8;
        bf16x8 kv = *(const bf16x8*)(Kb + base);
        bf16x8 vv = *(const bf16x8*)(Vb + base);
        *(bf16x8*)(Ks + l * KS + d8) = kv;
        #pragma unroll
        for (int j = 0; j < 8; ++j)
            Vt[(d8 + j) * VS + l] = (unsigned short)vv[j];
    }
    __syncthreads();

    bf16x8 fbK[2][2];
    #pragma unroll
    for (int n = 0; n < 2; ++n)
        #pragma unroll
        for (int ks = 0; ks < 2; ++ks)
            fbK[n][ks] = *(const bf16x8*)(Ks + (n * 16 + lr) * KS + ks * 32 + quad * 8);
    bf16x8 fbV[4];
    #pragma unroll
    for (int d = 0; d < 4; ++d)
        fbV[d] = *(const bf16x8*)(Vt + (d * 16 + lr) * VS + quad * 8);

    const size_t qbase = (size_t)b * 196 * 768 + (size_t)h * 64;

    for (int t = wave; t < 13; t += 4) {   // 13 tiles of 16 rows cover 196
        const int m0 = t * 16;
        int qrow = m0 + lr; if (qrow > 195) qrow = 195;  // clamp tail dups
        const unsigned short* qp = Q + qbase + (size_t)qrow * 768;
        bf16x8 fa0 = *(const bf16x8*)(qp + quad * 8);
        bf16x8 fa1 = *(const bf16x8*)(qp + 32 + quad * 8);
        f32x4 s0 = {}, s1 = {};
        s0 = __builtin_amdgcn_mfma_f32_16x16x32_bf16(fa0, fbK[0][0], s0, 0, 0, 0);
        s0 = __builtin_amdgcn_mfma_f32_16x16x32_bf16(fa1, fbK[0][1], s0, 0, 0, 0);
        s1 = __builtin_amdgcn_mfma_f32_16x16x32_bf16(fa0, fbK[1][0], s1, 0, 0, 0);
        s1 = __builtin_amdgcn_mfma_f32_16x16x32_bf16(fa1, fbK[1][1], s1, 0, 0, 0);

        float p0[4], p1[4], m4[4], s4[4];
        #pragma unroll
        for (int r = 0; r < 4; ++r) {
            p0[r] = s0[r] * 0.125f;
            p1[r] = s1[r] * 0.125f;
            m4[r] = fmaxf(p0[r], p1[r]);
        }
        #pragma unroll
        for (int off = 1; off < 16; off <<= 1)
            #pragma unroll
            for (int r = 0; r < 4; ++r)
                m4[r] = fmaxf(m4[r], __shfl_xor(m4[r], off));
        #pragma unroll
        for (int r = 0; r < 4; ++r) {
            p0[r] = __expf(p0[r] - m4[r]);
            p1[r] = __expf(p1[r] - m4[r]);
            s4[r] = p0[r] + p1[r];
        }
        #pragma unroll
        for (int off = 1; off < 16; off <<= 1)
            #pragma unroll
            for (int r = 0; r < 4; ++r)
                s4[r] += __shfl_xor(s4[r], off);
        #pragma unroll
        for (int r = 0; r < 4; ++r) {
            float inv = __builtin_amdgcn_rcpf(s4[r]);
            unsigned short* pr = &Pb[wave][(quad * 4 + r) * PS];
            pr[lr]      = f2bf(p0[r] * inv);
            pr[16 + lr] = f2bf(p1[r] * inv);
        }

        bf16x8 fap = *(const bf16x8*)(&Pb[wave][lr * PS + quad * 8]);
        f32x4 c[4];
        #pragma unroll
        for (int d = 0; d < 4; ++d) {
            f32x4 z = {};
            c[d] = __builtin_amdgcn_mfma_f32_16x16x32_bf16(fap, fbV[d], z, 0, 0, 0);
        }
        #pragma unroll
        for (int d = 0; d < 4; ++d)
            #pragma unroll
            for (int r = 0; r < 4; ++r)
                Cb[wave][(quad * 4 + r) * CS + d * 16 + lr] = f2bf(c[d][r]);
        #pragma unroll
        for (int i = 0; i < 2; ++i) {
            int c2 = lane + i * 64;
            int row = c2 >> 3, col8 = (c2 & 7) * 8;
            int grow = m0 + row;
            if (grow < 196) {
                bf16x8 cv = *(const bf16x8*)(&Cb[wave][row * CS + col8]);
                unsigned short* gp = RF + qbase + (size_t)grow * 768 + col8;
                bf16x8 rv = *(const bf16x8*)gp;
                bf16x8 ov;
                #pragma unroll
                for (int j = 0; j < 8; ++j)
                    ov[j] = (short)f2bf(bf2f((unsigned short)cv[j]) +
                                        bf2f((unsigned short)rv[j]));
                *(bf16x8*)gp = ov;
            }
        }
    }
}

// ---------------- MLP2: logits[m][0..1] = h[m] . W2 + b2 ; rel fill --------
__global__ __launch_bounds__(256)
void mlp2_kernel(const unsigned short* __restrict__ Hb,
                 const float* __restrict__ W2,   // [768][2]
                 const float* __restrict__ b2,
                 float* __restrict__ out) {
    __shared__ float w2s[2][768];
    const int tid = threadIdx.x;
    for (int i = tid; i < 1536; i += 256) w2s[i & 1][i >> 1] = W2[i];
    __syncthreads();
    const int sub = tid & 7;
    const int r = tid >> 3;                       // 0..31 rows per block
    const size_t row = (size_t)blockIdx.x * 32 + r;
    float a0 = 0.f, a1 = 0.f;
    #pragma unroll
    for (int i = 0; i < 12; ++i) {
        int base = i * 64 + sub * 8;
        bf16x8 hv = *(const bf16x8*)(Hb + row * 768 + base);
        #pragma unroll
        for (int j = 0; j < 8; ++j) {
            float hf = bf2f((unsigned short)hv[j]);
            a0 += hf * w2s[0][base + j];
            a1 += hf * w2s[1][base + j];
        }
    }
    #pragma unroll
    for (int o = 4; o >= 1; o >>= 1) {
        a0 += __shfl_down(a0, o, 8);
        a1 += __shfl_down(a1, o, 8);
    }
    if (sub == 0) {
        out[row * 2]      = a0 + b2[0];
        out[row * 2 + 1]  = a1 + b2[1];
        // rel_BN: softmax rows sum to 1 -> mean over Lt = 1/32, mean over H = 1/32
        out[100352 + row] = 0.03125f;
    }
}

extern "C" void kernel_launch(void* const* d_in, const int* in_sizes, int n_in,
                              void* d_out, int out_size, void* d_ws, size_t ws_size,
                              hipStream_t stream) {
    const float* vis = (const float*)d_in[0];
    const float* txt = (const float*)d_in[1];
    const float* Wq  = (const float*)d_in[2];
    const float* bq  = (const float*)d_in[3];
    const float* Wk  = (const float*)d_in[4];
    const float* bk  = (const float*)d_in[5];
    const float* Wv  = (const float*)d_in[6];
    const float* bv  = (const float*)d_in[7];
    const float* W1  = (const float*)d_in[8];
    const float* b1  = (const float*)d_in[9];
    const float* W2  = (const float*)d_in[10];
    const float* b2  = (const float*)d_in[11];
    float* out = (float*)d_out;

    char* w = (char*)d_ws;
    unsigned short* Abf = (unsigned short*)(w);              // 77,070,336 B (vis bf16; becomes "fused")
    unsigned short* Tbf = (unsigned short*)(w + 77070336);   //  8,388,608 B (text bf16)
    unsigned short* Wqt = (unsigned short*)(w + 85458944);   //  1,179,648 B
    unsigned short* Wkt = (unsigned short*)(w + 86638592);   //    786,432 B
    unsigned short* Wvt = (unsigned short*)(w + 87425024);   //    786,432 B
    unsigned short* W1t = (unsigned short*)(w + 88211456);   //  1,179,648 B
    unsigned short* Qbf = (unsigned short*)(w + 89391104);   // 77,070,336 B (Q; reused as H after attn)
    unsigned short* Kbf = (unsigned short*)(w + 166461440);  // 12,582,912 B
    unsigned short* Vbf = (unsigned short*)(w + 179044352);  // 12,582,912 B
    unsigned short* Hbf = Qbf;  // Q dead after attention

    cvt_bf16_kernel<<<37632, 256, 0, stream>>>(vis, Abf, 9633792);
    cvt_bf16_kernel<<<4096, 256, 0, stream>>>(txt, Tbf, 1048576);
    transpose_cvt_kernel<<<dim3(24, 24), 256, 0, stream>>>(Wq, Wqt, 768, 768);
    transpose_cvt_kernel<<<dim3(24, 16), 256, 0, stream>>>(Wk, Wkt, 512, 768);
    transpose_cvt_kernel<<<dim3(24, 16), 256, 0, stream>>>(Wv, Wvt, 512, 768);
    transpose_cvt_kernel<<<dim3(24, 24), 256, 0, stream>>>(W1, W1t, 768, 768);

    gemm256_kernel<768, 0><<<588, 512, 0, stream>>>(Abf, Wqt, bq, Qbf);
    gemm_bt_kernel<512, 0, 64><<<384, 256, 0, stream>>>(Tbf, Wkt, bk, Kbf);
    gemm_bt_kernel<512, 0, 64><<<384, 256, 0, stream>>>(Tbf, Wvt, bv, Vbf);

    attn_mfma_kernel<<<3072, 256, 0, stream>>>(Qbf, Kbf, Vbf, Abf);

    gemm256_kernel<768, 1><<<588, 512, 0, stream>>>(Abf, W1t, b1, Hbf);

    mlp2_kernel<<<1568, 256, 0, stream>>>(Hbf, W2, b2, out);
}

// Round 2
// 545.919 us; speedup vs baseline: 1.0263x; 1.0263x over previous
//
#include <hip/hip_runtime.h>
#include <hip/hip_bf16.h>

// Dims: B=256, Nv=196, Lt=32, Ci=768, Ct=512, H=12, D=64
// M1 = 50176 (=196*256), M2 = 8192 (=64*128), N = 768

typedef __attribute__((ext_vector_type(8))) short bf16x8;
typedef __attribute__((ext_vector_type(4))) float f32x4;

__device__ __forceinline__ float bf2f(unsigned short u) {
    return __uint_as_float(((unsigned int)u) << 16);
}
__device__ __forceinline__ unsigned short f2bf(float f) {
    unsigned int x = __float_as_uint(f);
    unsigned int r = (x + 0x7FFFu + ((x >> 16) & 1u)) >> 16;  // RNE
    return (unsigned short)r;
}

// async global->LDS, 16B/lane. LDS dest is wave-uniform base + lane*16.
#define GLOAD_LDS16(gp, lp)                                                    \
    __builtin_amdgcn_global_load_lds(                                          \
        (__attribute__((address_space(1))) void*)(gp),                         \
        (__attribute__((address_space(3))) void*)(lp), 16, 0, 0)

#define BAR()  __builtin_amdgcn_s_barrier()
#define LGKM0 asm volatile("s_waitcnt lgkmcnt(0)" ::: "memory")
#define VMC0  asm volatile("s_waitcnt vmcnt(0)" ::: "memory")
#define VMC4  asm volatile("s_waitcnt vmcnt(4)" ::: "memory")
#define VMC6  asm volatile("s_waitcnt vmcnt(6)" ::: "memory")

// ---------------- fp32 -> bf16 convert (vectorized) ----------------
__global__ void cvt_bf16_kernel(const float* __restrict__ in,
                                unsigned short* __restrict__ out, int n4) {
    int i = blockIdx.x * 256 + threadIdx.x;
    if (i >= n4) return;
    float4 v = ((const float4*)in)[i];
    ushort4 o;
    o.x = f2bf(v.x); o.y = f2bf(v.y); o.z = f2bf(v.z); o.w = f2bf(v.w);
    ((ushort4*)out)[i] = o;
}

// ---------------- W[K][N] -> Wt[N][K] transpose + bf16 ----------------
__global__ void transpose_cvt_kernel(const float* __restrict__ W,
                                     unsigned short* __restrict__ Wt,
                                     int K, int N) {
    __shared__ float tile[32][33];
    int n0 = blockIdx.x * 32, k0 = blockIdx.y * 32;
    int tx = threadIdx.x & 31, ty = threadIdx.x >> 5;  // 256 thr: ty 0..7
    #pragma unroll
    for (int r = ty; r < 32; r += 8)
        tile[r][tx] = W[(size_t)(k0 + r) * N + n0 + tx];
    __syncthreads();
    #pragma unroll
    for (int r = ty; r < 32; r += 8)
        Wt[(size_t)(n0 + r) * K + k0 + tx] = f2bf(tile[tx][r]);
}

// ---------------- 256x256 8-phase bf16 MFMA GEMM: C = A * Bt^T + bias ------
// T3+T4+T5 structure (learn_hip m201): BM=BN=256, BK=64, 8 waves (2Mx4N),
// 512 thr, double-buffered K-tiles, counted vmcnt(6) (never 0 in loop),
// raw s_barrier, setprio around each 16-MFMA quadrant.
// LDS layout = st_16x32 (m201): each K-tile stored as TWO k-panels
// (kk=0: k0..31, kk=1: k32..63), panel = [256 rows][32 bf16] row-major,
// row stride 64B. Swizzle: byte ^= ((byte>>9)&1)<<5 within each 1024B
// subtile (16 rows) -> slot-bit1 ^= row-bit3. Rows alternate bank
// half-windows (64B stride), XOR kills the 8-row alias: conflicts ~0 (m201).
// Staging stays global_load_lds (linear dest); the swizzle is applied by
// pre-swizzling the per-lane GLOBAL source (flip lane-bit1 by lane-bit5 --
// exact involution of the read-side XOR). One instr = 16 rows x one panel.
// Pipeline (per tile t, phases p0..p3):
//   reads:  p0: A-frags 0-3 (8) + B-frags 0-1 (4); p1: B 2-3 (4); p2: A 4-7 (8)
//   mfma:   p0 (Alo x Blo), p1 (Alo x Bhi), p2 (Ahi x Blo), p3 (Ahi x Bhi)
//   stages: p0: A1[t+1];  p2: B0[t+2];  p3: B1[t+2], A0[t+2], then vmcnt(6)
// Region safety: every stage lands after the phase whose lgkmcnt(0) drained
// the last read of that region (asm "memory" fences pin cross-phase motion).
template<int KTOT, int GELU>
__global__ __launch_bounds__(512, 1)
void gemm256_kernel(const unsigned short* __restrict__ A,
                    const unsigned short* __restrict__ Bt,
                    const float* __restrict__ bias,
                    unsigned short* __restrict__ C) {
    constexpr int NT = KTOT / 64;      // K-tiles (12 or 8)
    constexpr int PAN = 8192;          // shorts per k-panel (256 rows x 32)
    constexpr int TSZ = 2 * PAN;       // one 256x64 K-tile buffer
    __shared__ unsigned short As[2 * TSZ];   // 65,536 B
    __shared__ unsigned short Bs[2 * TSZ];   // 65,536 B (total 131,072 <= 160K)
    const int tid = threadIdx.x;
    const int lane = tid & 63, wave = tid >> 6;   // 8 waves
    const int wm = wave >> 2, wn = wave & 3;      // 2 x 4 wave grid
    const int lr = lane & 15, quad = lane >> 4;

    // bijective XCD swizzle (m204): consecutive wg on one XCD share A-panels
    const int nwg = gridDim.x;
    const int qq = nwg >> 3, r8 = nwg & 7;
    const int xcd = blockIdx.x & 7, loc = blockIdx.x >> 3;
    const int wg = (xcd < r8 ? xcd * (qq + 1) : r8 * (qq + 1) + (xcd - r8) * qq) + loc;
    const int mt = wg / 3, nt = wg - mt * 3;   // nt fastest: A-panel L2 reuse x3
    const size_t m0 = (size_t)mt * 256;
    const int n0 = nt * 256;

    // ---- read-side addressing (swizzled ds_read) ----
    // frag (rowblock i, kk): addr = buf + kk*PAN + row*32 + (quad ^ ((row>>3)&1)<<1)*8
    // with row = base + lr: (row>>3)&1 == (lr>>3)&1 (bases are 16-aligned).
    const int slotoff = ((quad ^ (((lr >> 3) & 1) << 1)) << 3);
    const int aBase = (wm * 128 + lr) * 32 + slotoff;   // + i*512 + kk*PAN
    const int bBase = (wn * 64 + lr) * 32 + slotoff;    // + j*512 + kk*PAN

    // ---- staging (pre-swizzled global source, linear LDS dest) ----
    // lane l covers row (l>>2), k-slot ((l&3) ^ ((l>>5)&1)<<1) of a
    // 16-row x 32-bf16 panel block.
    const int sg = (lane & 3) ^ (((lane >> 5) & 1) << 1);
    const unsigned short* gA = A + (m0 + (lane >> 2)) * (size_t)KTOT + sg * 8;
    const unsigned short* gB = Bt + ((size_t)(n0 + (lane >> 2))) * KTOT + sg * 8;
    // wave w stages units 2w,2w+1 of each 128-row half: panel sp, rows sr..sr+31
    const int sp = wave >> 2;              // 0..1 (panel)
    const int sr = (wave & 3) * 32;        // row base within half

#define STG_A(b, t, h) do {                                                    \
    const int r0_ = (h) * 128 + sr;                                            \
    GLOAD_LDS16(gA + (size_t)r0_ * KTOT + (t) * 64 + sp * 32,                  \
                As + (b) * TSZ + sp * PAN + r0_ * 32);                         \
    GLOAD_LDS16(gA + (size_t)(r0_ + 16) * KTOT + (t) * 64 + sp * 32,           \
                As + (b) * TSZ + sp * PAN + (r0_ + 16) * 32);                  \
} while (0)
#define STG_B(b, t, h) do {                                                    \
    const int r0_ = (h) * 128 + sr;                                            \
    GLOAD_LDS16(gB + (size_t)r0_ * KTOT + (t) * 64 + sp * 32,                  \
                Bs + (b) * TSZ + sp * PAN + r0_ * 32);                         \
    GLOAD_LDS16(gB + (size_t)(r0_ + 16) * KTOT + (t) * 64 + sp * 32,           \
                Bs + (b) * TSZ + sp * PAN + (r0_ + 16) * 32);                  \
} while (0)

    f32x4 acc[8][4] = {};
    bf16x8 aR[4][2], bR[4][2];

#define LDA_FRAGS(ibase)                                                       \
    _Pragma("unroll")                                                          \
    for (int i = 0; i < 4; ++i)                                                \
        _Pragma("unroll")                                                      \
        for (int kk = 0; kk < 2; ++kk)                                         \
            aR[i][kk] = *(const bf16x8*)(pa + kk * PAN + aBase + ((ibase) + i) * 512);

#define LDB_FRAGS(jbase)                                                       \
    _Pragma("unroll")                                                          \
    for (int j = 0; j < 2; ++j)                                                \
        _Pragma("unroll")                                                      \
        for (int kk = 0; kk < 2; ++kk)                                         \
            bR[(jbase) + j][kk] = *(const bf16x8*)(pb + kk * PAN + bBase + ((jbase) + j) * 512);

#define MFMA_Q(I0, J0)                                                         \
    __builtin_amdgcn_s_setprio(1);                                             \
    _Pragma("unroll")                                                          \
    for (int i = 0; i < 4; ++i)                                                \
        _Pragma("unroll")                                                      \
        for (int j = 0; j < 2; ++j)                                            \
            _Pragma("unroll")                                                  \
            for (int kk = 0; kk < 2; ++kk)                                     \
                acc[(I0) + i][(J0) + j] = __builtin_amdgcn_mfma_f32_16x16x32_bf16( \
                    aR[i][kk], bR[(J0) + j][kk], acc[(I0) + i][(J0) + j], 0, 0, 0); \
    __builtin_amdgcn_s_setprio(0);

    // prologue: tile0 fully, then 3 half-tiles of tile1; vmcnt(6) -> tile0 in
    STG_B(0, 0, 0); STG_B(0, 0, 1); STG_A(0, 0, 0); STG_A(0, 0, 1);
    VMC4;
    STG_B(1, 1, 0); STG_B(1, 1, 1); STG_A(1, 1, 0);
    VMC6;
    BAR();

    for (int t = 0; t < NT - 1; ++t) {
        const int buf = t & 1;
        const unsigned short* pa = As + buf * TSZ;
        const unsigned short* pb = Bs + buf * TSZ;
        const bool last = (t == NT - 2);
        // ---- p0 ----
        LDA_FRAGS(0); LDB_FRAGS(0);
        STG_A(buf ^ 1, t + 1, 1);
        BAR(); LGKM0;
        MFMA_Q(0, 0);
        BAR();
        // ---- p1 ----
        LDB_FRAGS(2);
        BAR(); LGKM0;
        MFMA_Q(0, 2);
        BAR();
        // ---- p2 ----
        LDA_FRAGS(4);
        if (!last) { STG_B(buf, t + 2, 0); } else { VMC4; }
        BAR(); LGKM0;
        MFMA_Q(4, 0);
        BAR();
        // ---- p3 ----
        if (!last) { STG_B(buf, t + 2, 1); STG_A(buf, t + 2, 0); VMC6; }
        else { VMC0; }
        BAR(); LGKM0;
        MFMA_Q(4, 2);
        BAR();
    }
    {   // tail tile NT-1: all data resident, reads+MFMA only
        const unsigned short* pa = As + ((NT - 1) & 1) * TSZ;
        const unsigned short* pb = Bs + ((NT - 1) & 1) * TSZ;
        LDA_FRAGS(0); LDB_FRAGS(0); LDB_FRAGS(2);
        MFMA_Q(0, 0);
        MFMA_Q(0, 2);
        LDA_FRAGS(4);
        MFMA_Q(4, 0);
        MFMA_Q(4, 2);
    }

    // epilogue: C/D layout col=lane&15, row=quad*4+reg  [m89-verified]
    // j innermost: a row's full 64-col (128B line) span completes within 4
    // consecutive stores -> no L2 dirty-line eviction between pieces.
    float bvv[4];
    #pragma unroll
    for (int j = 0; j < 4; ++j)
        bvv[j] = bias[n0 + wn * 64 + j * 16 + lr];
    #pragma unroll
    for (int i = 0; i < 8; ++i) {
        #pragma unroll
        for (int r2 = 0; r2 < 4; ++r2) {
            size_t row = m0 + wm * 128 + i * 16 + quad * 4 + r2;
            unsigned short* cp = C + row * 768 + n0 + wn * 64 + lr;
            #pragma unroll
            for (int j = 0; j < 4; ++j) {
                float x = acc[i][j][r2] + bvv[j];
                if (GELU) x = x / (1.0f + __expf(-1.702f * x));  // quick_gelu
                cp[j * 16] = f2bf(x);
            }
        }
    }
#undef STG_A
#undef STG_B
#undef LDA_FRAGS
#undef LDB_FRAGS
#undef MFMA_Q
}

// ---------------- bf16 MFMA GEMM (m97 structure), kept for small K/V -------
template<int KTOT, int GELU, int MTILES>
__global__ __launch_bounds__(256, 2)
void gemm_bt_kernel(const unsigned short* __restrict__ A,
                    const unsigned short* __restrict__ Bt,
                    const float* __restrict__ bias,
                    unsigned short* __restrict__ C) {
    constexpr int GS = 520;  // 8-row group stride in shorts (512 + 8 pad)
    __shared__ unsigned short As[16 * GS];
    __shared__ unsigned short Bs[16 * GS];
    const int tid = threadIdx.x;
    const int lane = tid & 63, wave = tid >> 6;
    const int id = blockIdx.x;
    const int xcd = id & 7, local = id >> 3;
    const int nt = local % 6, mt = xcd * (MTILES / 8) + local / 6;
    const size_t m0 = (size_t)mt * 128;
    const int n0 = nt * 128;
    const int wm = (wave >> 1) * 64, wn = (wave & 1) * 64;
    const int lr = lane & 15, quad = lane >> 4;

    const int swz = ((lane & 7) ^ (lane >> 3)) * 8;
    const unsigned short* gA = A + (m0 + wave * 32 + (lane >> 3)) * KTOT + swz;
    const unsigned short* gB = Bt + ((size_t)n0 + wave * 32 + (lane >> 3)) * KTOT + swz;
    unsigned short* lA = As + (wave * 4) * GS;
    unsigned short* lB = Bs + (wave * 4) * GS;

    f32x4 acc[4][4] = {};

    for (int kt = 0; kt < KTOT; kt += 64) {
        #pragma unroll
        for (int i = 0; i < 4; ++i) {
            GLOAD_LDS16(gA + (size_t)i * 8 * KTOT + kt, lA + i * GS);
            GLOAD_LDS16(gB + (size_t)i * 8 * KTOT + kt, lB + i * GS);
        }
        __syncthreads();
        #pragma unroll
        for (int kk = 0; kk < 64; kk += 32) {
            bf16x8 fa[4], fb[4];
            #pragma unroll
            for (int i = 0; i < 4; ++i) {
                int r = wm + i * 16 + lr;
                int g = (kk >> 3) + quad;
                fa[i] = *(const bf16x8*)(As + (r >> 3) * GS + (r & 7) * 64 +
                                         ((g ^ (r & 7)) << 3));
            }
            #pragma unroll
            for (int j = 0; j < 4; ++j) {
                int r = wn + j * 16 + lr;
                int g = (kk >> 3) + quad;
                fb[j] = *(const bf16x8*)(Bs + (r >> 3) * GS + (r & 7) * 64 +
                                         ((g ^ (r & 7)) << 3));
            }
            #pragma unroll
            for (int i = 0; i < 4; ++i)
                #pragma unroll
                for (int j = 0; j < 4; ++j)
                    acc[i][j] = __builtin_amdgcn_mfma_f32_16x16x32_bf16(
                        fa[i], fb[j], acc[i][j], 0, 0, 0);
        }
        __syncthreads();
    }

    #pragma unroll
    for (int j = 0; j < 4; ++j) {
        int col = n0 + wn + j * 16 + lr;
        float bv = bias[col];
        #pragma unroll
        for (int i = 0; i < 4; ++i) {
            #pragma unroll
            for (int r = 0; r < 4; ++r) {
                size_t row = m0 + wm + i * 16 + quad * 4 + r;
                float x = acc[i][j][r] + bv;
                if (GELU) x = x / (1.0f + __expf(-1.702f * x));
                C[row * 768 + col] = f2bf(x);
            }
        }
    }
}

// ---------------- MFMA attention: one block per (b,h), 4 waves -------------
__global__ __launch_bounds__(256, 4)
void attn_mfma_kernel(const unsigned short* __restrict__ Q,
                      const unsigned short* __restrict__ Kb,
                      const unsigned short* __restrict__ Vb,
                      unsigned short* __restrict__ RF) {
    constexpr int KS = 72;  // Ks row stride
    constexpr int VS = 34;  // Vt row stride
    constexpr int PS = 40;  // P row stride
    constexpr int CS = 72;  // ctx row stride
    __shared__ unsigned short Ks[32 * KS];      // K rows  [l][d]
    __shared__ unsigned short Vt[64 * VS];      // V^T     [d][l]
    __shared__ unsigned short Pb[4][16 * PS];   // per-wave P  [m][l]
    __shared__ unsigned short Cb[4][16 * CS];   // per-wave ctx[m][d]
    const int tid = threadIdx.x;
    const int b = blockIdx.x / 12, h = blockIdx.x % 12;
    const int lane = tid & 63, wave = tid >> 6;
    const int lr = lane & 15, quad = lane >> 4;

    {   // stage K rows + V transposed (bf16, one-time)
        int l = tid >> 3, d8 = (tid & 7) * 8;
        size_t base = ((size_t)b * 32 + l) * 768 + (size_t)h * 64 + d8;
        bf16x8 kv = *(const bf16x8*)(Kb + base);
        bf16x8 vv = *(const bf16x8*)(Vb + base);
        *(bf16x8*)(Ks + l * KS + d8) = kv;
        #pragma unroll
        for (int j = 0; j < 8; ++j)
            Vt[(d8 + j) * VS + l] = (unsigned short)vv[j];
    }
    __syncthreads();

    bf16x8 fbK[2][2];
    #pragma unroll
    for (int n = 0; n < 2; ++n)
        #pragma unroll
        for (int ks = 0; ks < 2; ++ks)
            fbK[n][ks] = *(const bf16x8*)(Ks + (n * 16 + lr) * KS + ks * 32 + quad * 8);
    bf16x8 fbV[4];
    #pragma unroll
    for (int d = 0; d < 4; ++d)
        fbV[d] = *(const bf16x8*)(Vt + (d * 16 + lr) * VS + quad * 8);

    const size_t qbase = (size_t)b * 196 * 768 + (size_t)h * 64;

    for (int t = wave; t < 13; t += 4) {   // 13 tiles of 16 rows cover 196
        const int m0 = t * 16;
        int qrow = m0 + lr; if (qrow > 195) qrow = 195;  // clamp tail dups
        const unsigned short* qp = Q + qbase + (size_t)qrow * 768;
        bf16x8 fa0 = *(const bf16x8*)(qp + quad * 8);
        bf16x8 fa1 = *(const bf16x8*)(qp + 32 + quad * 8);
        f32x4 s0 = {}, s1 = {};
        s0 = __builtin_amdgcn_mfma_f32_16x16x32_bf16(fa0, fbK[0][0], s0, 0, 0, 0);
        s0 = __builtin_amdgcn_mfma_f32_16x16x32_bf16(fa1, fbK[0][1], s0, 0, 0, 0);
        s1 = __builtin_amdgcn_mfma_f32_16x16x32_bf16(fa0, fbK[1][0], s1, 0, 0, 0);
        s1 = __builtin_amdgcn_mfma_f32_16x16x32_bf16(fa1, fbK[1][1], s1, 0, 0, 0);

        float p0[4], p1[4], m4[4], s4[4];
        #pragma unroll
        for (int r = 0; r < 4; ++r) {
            p0[r] = s0[r] * 0.125f;
            p1[r] = s1[r] * 0.125f;
            m4[r] = fmaxf(p0[r], p1[r]);
        }
        #pragma unroll
        for (int off = 1; off < 16; off <<= 1)
            #pragma unroll
            for (int r = 0; r < 4; ++r)
                m4[r] = fmaxf(m4[r], __shfl_xor(m4[r], off));
        #pragma unroll
        for (int r = 0; r < 4; ++r) {
            p0[r] = __expf(p0[r] - m4[r]);
            p1[r] = __expf(p1[r] - m4[r]);
            s4[r] = p0[r] + p1[r];
        }
        #pragma unroll
        for (int off = 1; off < 16; off <<= 1)
            #pragma unroll
            for (int r = 0; r < 4; ++r)
                s4[r] += __shfl_xor(s4[r], off);
        #pragma unroll
        for (int r = 0; r < 4; ++r) {
            float inv = __builtin_amdgcn_rcpf(s4[r]);
            unsigned short* pr = &Pb[wave][(quad * 4 + r) * PS];
            pr[lr]      = f2bf(p0[r] * inv);
            pr[16 + lr] = f2bf(p1[r] * inv);
        }

        bf16x8 fap = *(const bf16x8*)(&Pb[wave][lr * PS + quad * 8]);
        f32x4 c[4];
        #pragma unroll
        for (int d = 0; d < 4; ++d) {
            f32x4 z = {};
            c[d] = __builtin_amdgcn_mfma_f32_16x16x32_bf16(fap, fbV[d], z, 0, 0, 0);
        }
        #pragma unroll
        for (int d = 0; d < 4; ++d)
            #pragma unroll
            for (int r = 0; r < 4; ++r)
                Cb[wave][(quad * 4 + r) * CS + d * 16 + lr] = f2bf(c[d][r]);
        #pragma unroll
        for (int i = 0; i < 2; ++i) {
            int c2 = lane + i * 64;
            int row = c2 >> 3, col8 = (c2 & 7) * 8;
            int grow = m0 + row;
            if (grow < 196) {
                bf16x8 cv = *(const bf16x8*)(&Cb[wave][row * CS + col8]);
                unsigned short* gp = RF + qbase + (size_t)grow * 768 + col8;
                bf16x8 rv = *(const bf16x8*)gp;
                bf16x8 ov;
                #pragma unroll
                for (int j = 0; j < 8; ++j)
                    ov[j] = (short)f2bf(bf2f((unsigned short)cv[j]) +
                                        bf2f((unsigned short)rv[j]));
                *(bf16x8*)gp = ov;
            }
        }
    }
}

// ---------------- MLP2: logits[m][0..1] = h[m] . W2 + b2 ; rel fill --------
__global__ __launch_bounds__(256)
void mlp2_kernel(const unsigned short* __restrict__ Hb,
                 const float* __restrict__ W2,   // [768][2]
                 const float* __restrict__ b2,
                 float* __restrict__ out) {
    __shared__ float w2s[2][768];
    const int tid = threadIdx.x;
    for (int i = tid; i < 1536; i += 256) w2s[i & 1][i >> 1] = W2[i];
    __syncthreads();
    const int sub = tid & 7;
    const int r = tid >> 3;                       // 0..31 rows per block
    const size_t row = (size_t)blockIdx.x * 32 + r;
    float a0 = 0.f, a1 = 0.f;
    #pragma unroll
    for (int i = 0; i < 12; ++i) {
        int base = i * 64 + sub * 8;
        bf16x8 hv = *(const bf16x8*)(Hb + row * 768 + base);
        #pragma unroll
        for (int j = 0; j < 8; ++j) {
            float hf = bf2f((unsigned short)hv[j]);
            a0 += hf * w2s[0][base + j];
            a1 += hf * w2s[1][base + j];
        }
    }
    #pragma unroll
    for (int o = 4; o >= 1; o >>= 1) {
        a0 += __shfl_down(a0, o, 8);
        a1 += __shfl_down(a1, o, 8);
    }
    if (sub == 0) {
        out[row * 2]      = a0 + b2[0];
        out[row * 2 + 1]  = a1 + b2[1];
        // rel_BN: softmax rows sum to 1 -> mean over Lt = 1/32, mean over H = 1/32
        out[100352 + row] = 0.03125f;
    }
}

extern "C" void kernel_launch(void* const* d_in, const int* in_sizes, int n_in,
                              void* d_out, int out_size, void* d_ws, size_t ws_size,
                              hipStream_t stream) {
    const float* vis = (const float*)d_in[0];
    const float* txt = (const float*)d_in[1];
    const float* Wq  = (const float*)d_in[2];
    const float* bq  = (const float*)d_in[3];
    const float* Wk  = (const float*)d_in[4];
    const float* bk  = (const float*)d_in[5];
    const float* Wv  = (const float*)d_in[6];
    const float* bv  = (const float*)d_in[7];
    const float* W1  = (const float*)d_in[8];
    const float* b1  = (const float*)d_in[9];
    const float* W2  = (const float*)d_in[10];
    const float* b2  = (const float*)d_in[11];
    float* out = (float*)d_out;

    char* w = (char*)d_ws;
    unsigned short* Abf = (unsigned short*)(w);              // 77,070,336 B (vis bf16; becomes "fused")
    unsigned short* Tbf = (unsigned short*)(w + 77070336);   //  8,388,608 B (text bf16)
    unsigned short* Wqt = (unsigned short*)(w + 85458944);   //  1,179,648 B
    unsigned short* Wkt = (unsigned short*)(w + 86638592);   //    786,432 B
    unsigned short* Wvt = (unsigned short*)(w + 87425024);   //    786,432 B
    unsigned short* W1t = (unsigned short*)(w + 88211456);   //  1,179,648 B
    unsigned short* Qbf = (unsigned short*)(w + 89391104);   // 77,070,336 B (Q; reused as H after attn)
    unsigned short* Kbf = (unsigned short*)(w + 166461440);  // 12,582,912 B
    unsigned short* Vbf = (unsigned short*)(w + 179044352);  // 12,582,912 B
    unsigned short* Hbf = Qbf;  // Q dead after attention

    cvt_bf16_kernel<<<37632, 256, 0, stream>>>(vis, Abf, 9633792);
    cvt_bf16_kernel<<<4096, 256, 0, stream>>>(txt, Tbf, 1048576);
    transpose_cvt_kernel<<<dim3(24, 24), 256, 0, stream>>>(Wq, Wqt, 768, 768);
    transpose_cvt_kernel<<<dim3(24, 16), 256, 0, stream>>>(Wk, Wkt, 512, 768);
    transpose_cvt_kernel<<<dim3(24, 16), 256, 0, stream>>>(Wv, Wvt, 512, 768);
    transpose_cvt_kernel<<<dim3(24, 24), 256, 0, stream>>>(W1, W1t, 768, 768);

    gemm256_kernel<768, 0><<<588, 512, 0, stream>>>(Abf, Wqt, bq, Qbf);
    gemm_bt_kernel<512, 0, 64><<<384, 256, 0, stream>>>(Tbf, Wkt, bk, Kbf);
    gemm_bt_kernel<512, 0, 64><<<384, 256, 0, stream>>>(Tbf, Wvt, bv, Vbf);

    attn_mfma_kernel<<<3072, 256, 0, stream>>>(Qbf, Kbf, Vbf, Abf);

    gemm256_kernel<768, 1><<<588, 512, 0, stream>>>(Abf, W1t, b1, Hbf);

    mlp2_kernel<<<1568, 256, 0, stream>>>(Hbf, W2, b2, out);
}

// Round 3
// 511.246 us; speedup vs baseline: 1.0959x; 1.0678x over previous
//
#include <hip/hip_runtime.h>
#include <hip/hip_bf16.h>

// Dims: B=256, Nv=196, Lt=32, Ci=768, Ct=512, H=12, D=64
// M1 = 50176 (=392*128), M2 = 8192 (=64*128), N = 768 (=6*128)

typedef __attribute__((ext_vector_type(8))) short bf16x8;
typedef __attribute__((ext_vector_type(4))) float f32x4;

__device__ __forceinline__ float bf2f(unsigned short u) {
    return __uint_as_float(((unsigned int)u) << 16);
}
__device__ __forceinline__ unsigned short f2bf(float f) {
    unsigned int x = __float_as_uint(f);
    unsigned int r = (x + 0x7FFFu + ((x >> 16) & 1u)) >> 16;  // RNE
    return (unsigned short)r;
}

// async global->LDS, 16B/lane. LDS dest is wave-uniform base + lane*16.
#define GLOAD_LDS16(gp, lp)                                                    \
    __builtin_amdgcn_global_load_lds(                                          \
        (__attribute__((address_space(1))) void*)(gp),                         \
        (__attribute__((address_space(3))) void*)(lp), 16, 0, 0)

#define BAR()  __builtin_amdgcn_s_barrier()
#define SCHED0 __builtin_amdgcn_sched_barrier(0)
#define VMC0  asm volatile("s_waitcnt vmcnt(0)" ::: "memory")
#define VMC8  asm volatile("s_waitcnt vmcnt(8)" ::: "memory")

// ---------------- fp32 -> bf16 convert (both tensors, one launch) ----------
__global__ void cvt2_kernel(const float* __restrict__ in0,
                            unsigned short* __restrict__ out0, int n0,
                            const float* __restrict__ in1,
                            unsigned short* __restrict__ out1) {
    int i = blockIdx.x * 256 + threadIdx.x;
    const float* in = in0; unsigned short* out = out0;
    if (i >= n0) { i -= n0; in = in1; out = out1; }
    float4 v = ((const float4*)in)[i];
    ushort4 o;
    o.x = f2bf(v.x); o.y = f2bf(v.y); o.z = f2bf(v.z); o.w = f2bf(v.w);
    ((ushort4*)out)[i] = o;
}

// ---------------- all four W[K][N] -> Wt[N][K] transposes, one launch ------
__global__ void transpose4_kernel(const float* __restrict__ Wq, unsigned short* __restrict__ Wqt,
                                  const float* __restrict__ Wk, unsigned short* __restrict__ Wkt,
                                  const float* __restrict__ Wv, unsigned short* __restrict__ Wvt,
                                  const float* __restrict__ W1, unsigned short* __restrict__ W1t) {
    __shared__ float tile[32][33];
    int id = blockIdx.x;
    const float* W; unsigned short* Wt; int K;
    if (id < 576)       { W = Wq; Wt = Wqt; K = 768; }
    else if (id < 960)  { id -= 576;  W = Wk; Wt = Wkt; K = 512; }
    else if (id < 1344) { id -= 960;  W = Wv; Wt = Wvt; K = 512; }
    else                { id -= 1344; W = W1; Wt = W1t; K = 768; }
    int n0 = (id % 24) * 32, k0 = (id / 24) * 32;
    int tx = threadIdx.x & 31, ty = threadIdx.x >> 5;  // 256 thr: ty 0..7
    #pragma unroll
    for (int r = ty; r < 32; r += 8)
        tile[r][tx] = W[(size_t)(k0 + r) * 768 + n0 + tx];
    __syncthreads();
    #pragma unroll
    for (int r = ty; r < 32; r += 8)
        Wt[(size_t)(n0 + r) * K + k0 + tx] = f2bf(tile[tx][r]);
}

// ---------------- 128x128 bf16 MFMA GEMM, double-buffered counted-vmcnt ----
// m97 structure + T2 (st_16x32 zero-conflict layout, validated R2) + T4-min
// (dbuf LDS, STAGE(t+2) issued after read-barrier, counted vmcnt(8) so the
// next tile's 8 loads stay in flight across a full compute phase ~1400 cy >
// HBM latency ~900 cy). 4 waves (2x2), 2 blocks/CU (64 KB LDS, VGPR<=128).
// LDS layout per K-tile: 2 k-panels [128 rows][32 bf16], row stride 64B;
// swizzle: slot-bit1 ^= row-bit3 (16-row subtile XOR). Staging: linear LDS
// dest (global_load_lds), inverse-swizzled per-lane GLOBAL source
// (lane&3 ^= (lane>>5)&1 <<1) -- exact involution of the read-side XOR.
// Schedule per iter t:
//   COMPUTE(buf t&1)     (16 ds_read_b128 + 32 MFMA, compiler lgkm waits)
//   BAR                  (all waves done reading buf)
//   STG(buf t&1, t+2); VMC8   (drain t+1's loads; t+2's fly on)
//   BAR                  (buf (t+1)&1 complete chip-wide)
template<int KTOT, int GELU, int MTILES>
__device__ __forceinline__
void gemm_body(int id, const unsigned short* __restrict__ A,
               const unsigned short* __restrict__ Bt,
               const float* __restrict__ bias,
               unsigned short* __restrict__ C,
               unsigned short* As, unsigned short* Bs) {
    constexpr int NT = KTOT / 64;
    constexpr int PAN = 4096;          // 128 rows x 32 shorts (one k-panel)
    constexpr int TSZ = 2 * PAN;       // one 128x64 K-tile
    const int tid = threadIdx.x;
    const int lane = tid & 63, wave = tid >> 6;        // 4 waves
    const int wm = (wave >> 1) * 64, wn = (wave & 1) * 64;
    const int lr = lane & 15, quad = lane >> 4;

    // XCD-chunked tile mapping (grid % 8 == 0 for all uses)
    const int xcd = id & 7, local = id >> 3;
    const int nt = local % 6, mt = xcd * (MTILES / 8) + local / 6;
    const size_t m0 = (size_t)mt * 128;
    const int n0 = nt * 128;

    // read-side swizzled addressing
    const int slotoff = ((quad ^ (((lr >> 3) & 1) << 1)) << 3);
    const int aBase = (wm + lr) * 32 + slotoff;        // + i*512 + kk*PAN
    const int bBase = (wn + lr) * 32 + slotoff;

    // staging source (pre-swizzled global): lane -> row lane>>2, slot lane&3
    const int sg = (lane & 3) ^ (((lane >> 5) & 1) << 1);
    const unsigned short* gA = A + (m0 + (lane >> 2)) * (size_t)KTOT + sg * 8;
    const unsigned short* gB = Bt + ((size_t)n0 + (lane >> 2)) * KTOT + sg * 8;
    const int sr = wave * 32;   // wave's 32-row strip (2 x 16-row blocks)

#define STG(b, t) do {                                                         \
    _Pragma("unroll")                                                          \
    for (int p_ = 0; p_ < 2; ++p_) {                                           \
        _Pragma("unroll")                                                      \
        for (int q_ = 0; q_ < 2; ++q_) {                                       \
            const int r0_ = sr + q_ * 16;                                      \
            GLOAD_LDS16(gA + (size_t)r0_ * KTOT + (t) * 64 + p_ * 32,          \
                        As + (b) * TSZ + p_ * PAN + r0_ * 32);                 \
            GLOAD_LDS16(gB + (size_t)r0_ * KTOT + (t) * 64 + p_ * 32,          \
                        Bs + (b) * TSZ + p_ * PAN + r0_ * 32);                 \
        }                                                                      \
    }                                                                          \
} while (0)

    f32x4 acc[4][4] = {};

#define COMPUTE(bsel) do {                                                     \
    const unsigned short* pa = As + (bsel) * TSZ;                              \
    const unsigned short* pb = Bs + (bsel) * TSZ;                              \
    _Pragma("unroll")                                                          \
    for (int kk = 0; kk < 2; ++kk) {                                           \
        bf16x8 fa[4], fb[4];                                                   \
        _Pragma("unroll")                                                      \
        for (int i = 0; i < 4; ++i)                                            \
            fa[i] = *(const bf16x8*)(pa + kk * PAN + aBase + i * 512);         \
        _Pragma("unroll")                                                      \
        for (int j = 0; j < 4; ++j)                                            \
            fb[j] = *(const bf16x8*)(pb + kk * PAN + bBase + j * 512);         \
        _Pragma("unroll")                                                      \
        for (int i = 0; i < 4; ++i)                                            \
            _Pragma("unroll")                                                  \
            for (int j = 0; j < 4; ++j)                                        \
                acc[i][j] = __builtin_amdgcn_mfma_f32_16x16x32_bf16(           \
                    fa[i], fb[j], acc[i][j], 0, 0, 0);                         \
    }                                                                          \
} while (0)

    // prologue: tiles 0,1 staged; drain tile0 (oldest 8), tile1 in flight
    STG(0, 0);
    STG(1, 1);
    VMC8;
    BAR(); SCHED0;

    for (int t = 0; t < NT - 1; ++t) {
        COMPUTE(t & 1);
        BAR(); SCHED0;                         // all waves done reading buf
        if (t + 2 < NT) { STG(t & 1, t + 2); VMC8; }
        else            { VMC0; }
        BAR(); SCHED0;                         // tile t+1 resident chip-wide
    }
    COMPUTE((NT - 1) & 1);

    // epilogue: C/D layout col=lane&15, row=quad*4+reg [m89-verified];
    // j innermost so each row's 128B span completes in 4 consecutive stores.
    float bvv[4];
    #pragma unroll
    for (int j = 0; j < 4; ++j)
        bvv[j] = bias[n0 + wn + j * 16 + lr];
    #pragma unroll
    for (int i = 0; i < 4; ++i) {
        #pragma unroll
        for (int r2 = 0; r2 < 4; ++r2) {
            size_t row = m0 + wm + i * 16 + quad * 4 + r2;
            unsigned short* cp = C + row * 768 + n0 + wn + lr;
            #pragma unroll
            for (int j = 0; j < 4; ++j) {
                float x = acc[i][j][r2] + bvv[j];
                if (GELU) x = x / (1.0f + __expf(-1.702f * x));  // quick_gelu
                cp[j * 16] = f2bf(x);
            }
        }
    }
#undef STG
#undef COMPUTE
}

template<int KTOT, int GELU, int MTILES>
__global__ __launch_bounds__(256, 2)
void gemm_db_kernel(const unsigned short* __restrict__ A,
                    const unsigned short* __restrict__ Bt,
                    const float* __restrict__ bias,
                    unsigned short* __restrict__ C) {
    __shared__ unsigned short As[2 * 8192];   // 32 KB
    __shared__ unsigned short Bs[2 * 8192];   // 32 KB
    gemm_body<KTOT, GELU, MTILES>(blockIdx.x, A, Bt, bias, C, As, Bs);
}

// K and V projections in ONE dispatch (share A=Tbf in L2)
template<int KTOT, int MTILES>
__global__ __launch_bounds__(256, 2)
void gemm_kv_kernel(const unsigned short* __restrict__ A,
                    const unsigned short* __restrict__ Bt0,
                    const float* __restrict__ bias0,
                    unsigned short* __restrict__ C0,
                    const unsigned short* __restrict__ Bt1,
                    const float* __restrict__ bias1,
                    unsigned short* __restrict__ C1) {
    __shared__ unsigned short As[2 * 8192];
    __shared__ unsigned short Bs[2 * 8192];
    const int half = gridDim.x >> 1;
    if (blockIdx.x < half)
        gemm_body<KTOT, 0, MTILES>(blockIdx.x, A, Bt0, bias0, C0, As, Bs);
    else
        gemm_body<KTOT, 0, MTILES>(blockIdx.x - half, A, Bt1, bias1, C1, As, Bs);
}

// ---------------- MFMA attention: one block per (b,h), 4 waves -------------
__global__ __launch_bounds__(256, 4)
void attn_mfma_kernel(const unsigned short* __restrict__ Q,
                      const unsigned short* __restrict__ Kb,
                      const unsigned short* __restrict__ Vb,
                      unsigned short* __restrict__ RF) {
    constexpr int KS = 72;  // Ks row stride
    constexpr int VS = 34;  // Vt row stride
    constexpr int PS = 40;  // P row stride
    constexpr int CS = 72;  // ctx row stride
    __shared__ unsigned short Ks[32 * KS];      // K rows  [l][d]
    __shared__ unsigned short Vt[64 * VS];      // V^T     [d][l]
    __shared__ unsigned short Pb[4][16 * PS];   // per-wave P  [m][l]
    __shared__ unsigned short Cb[4][16 * CS];   // per-wave ctx[m][d]
    const int tid = threadIdx.x;
    const int b = blockIdx.x / 12, h = blockIdx.x % 12;
    const int lane = tid & 63, wave = tid >> 6;
    const int lr = lane & 15, quad = lane >> 4;

    {   // stage K rows + V transposed (bf16, one-time)
        int l = tid >> 3, d8 = (tid & 7) * 8;
        size_t base = ((size_t)b * 32 + l) * 768 + (size_t)h * 64 + d8;
        bf16x8 kv = *(const bf16x8*)(Kb + base);
        bf16x8 vv = *(const bf16x8*)(Vb + base);
        *(bf16x8*)(Ks + l * KS + d8) = kv;
        #pragma unroll
        for (int j = 0; j < 8; ++j)
            Vt[(d8 + j) * VS + l] = (unsigned short)vv[j];
    }
    __syncthreads();

    bf16x8 fbK[2][2];
    #pragma unroll
    for (int n = 0; n < 2; ++n)
        #pragma unroll
        for (int ks = 0; ks < 2; ++ks)
            fbK[n][ks] = *(const bf16x8*)(Ks + (n * 16 + lr) * KS + ks * 32 + quad * 8);
    bf16x8 fbV[4];
    #pragma unroll
    for (int d = 0; d < 4; ++d)
        fbV[d] = *(const bf16x8*)(Vt + (d * 16 + lr) * VS + quad * 8);

    const size_t qbase = (size_t)b * 196 * 768 + (size_t)h * 64;

    for (int t = wave; t < 13; t += 4) {   // 13 tiles of 16 rows cover 196
        const int m0 = t * 16;
        int qrow = m0 + lr; if (qrow > 195) qrow = 195;  // clamp tail dups
        const unsigned short* qp = Q + qbase + (size_t)qrow * 768;
        bf16x8 fa0 = *(const bf16x8*)(qp + quad * 8);
        bf16x8 fa1 = *(const bf16x8*)(qp + 32 + quad * 8);
        f32x4 s0 = {}, s1 = {};
        s0 = __builtin_amdgcn_mfma_f32_16x16x32_bf16(fa0, fbK[0][0], s0, 0, 0, 0);
        s0 = __builtin_amdgcn_mfma_f32_16x16x32_bf16(fa1, fbK[0][1], s0, 0, 0, 0);
        s1 = __builtin_amdgcn_mfma_f32_16x16x32_bf16(fa0, fbK[1][0], s1, 0, 0, 0);
        s1 = __builtin_amdgcn_mfma_f32_16x16x32_bf16(fa1, fbK[1][1], s1, 0, 0, 0);

        float p0[4], p1[4], m4[4], s4[4];
        #pragma unroll
        for (int r = 0; r < 4; ++r) {
            p0[r] = s0[r] * 0.125f;
            p1[r] = s1[r] * 0.125f;
            m4[r] = fmaxf(p0[r], p1[r]);
        }
        #pragma unroll
        for (int off = 1; off < 16; off <<= 1)
            #pragma unroll
            for (int r = 0; r < 4; ++r)
                m4[r] = fmaxf(m4[r], __shfl_xor(m4[r], off));
        #pragma unroll
        for (int r = 0; r < 4; ++r) {
            p0[r] = __expf(p0[r] - m4[r]);
            p1[r] = __expf(p1[r] - m4[r]);
            s4[r] = p0[r] + p1[r];
        }
        #pragma unroll
        for (int off = 1; off < 16; off <<= 1)
            #pragma unroll
            for (int r = 0; r < 4; ++r)
                s4[r] += __shfl_xor(s4[r], off);
        #pragma unroll
        for (int r = 0; r < 4; ++r) {
            float inv = __builtin_amdgcn_rcpf(s4[r]);
            unsigned short* pr = &Pb[wave][(quad * 4 + r) * PS];
            pr[lr]      = f2bf(p0[r] * inv);
            pr[16 + lr] = f2bf(p1[r] * inv);
        }

        bf16x8 fap = *(const bf16x8*)(&Pb[wave][lr * PS + quad * 8]);
        f32x4 c[4];
        #pragma unroll
        for (int d = 0; d < 4; ++d) {
            f32x4 z = {};
            c[d] = __builtin_amdgcn_mfma_f32_16x16x32_bf16(fap, fbV[d], z, 0, 0, 0);
        }
        #pragma unroll
        for (int d = 0; d < 4; ++d)
            #pragma unroll
            for (int r = 0; r < 4; ++r)
                Cb[wave][(quad * 4 + r) * CS + d * 16 + lr] = f2bf(c[d][r]);
        #pragma unroll
        for (int i = 0; i < 2; ++i) {
            int c2 = lane + i * 64;
            int row = c2 >> 3, col8 = (c2 & 7) * 8;
            int grow = m0 + row;
            if (grow < 196) {
                bf16x8 cv = *(const bf16x8*)(&Cb[wave][row * CS + col8]);
                unsigned short* gp = RF + qbase + (size_t)grow * 768 + col8;
                bf16x8 rv = *(const bf16x8*)gp;
                bf16x8 ov;
                #pragma unroll
                for (int j = 0; j < 8; ++j)
                    ov[j] = (short)f2bf(bf2f((unsigned short)cv[j]) +
                                        bf2f((unsigned short)rv[j]));
                *(bf16x8*)gp = ov;
            }
        }
    }
}

// ---------------- MLP2: logits[m][0..1] = h[m] . W2 + b2 ; rel fill --------
__global__ __launch_bounds__(256)
void mlp2_kernel(const unsigned short* __restrict__ Hb,
                 const float* __restrict__ W2,   // [768][2]
                 const float* __restrict__ b2,
                 float* __restrict__ out) {
    __shared__ float w2s[2][768];
    const int tid = threadIdx.x;
    for (int i = tid; i < 1536; i += 256) w2s[i & 1][i >> 1] = W2[i];
    __syncthreads();
    const int sub = tid & 7;
    const int r = tid >> 3;                       // 0..31 rows per block
    const size_t row = (size_t)blockIdx.x * 32 + r;
    float a0 = 0.f, a1 = 0.f;
    #pragma unroll
    for (int i = 0; i < 12; ++i) {
        int base = i * 64 + sub * 8;
        bf16x8 hv = *(const bf16x8*)(Hb + row * 768 + base);
        #pragma unroll
        for (int j = 0; j < 8; ++j) {
            float hf = bf2f((unsigned short)hv[j]);
            a0 += hf * w2s[0][base + j];
            a1 += hf * w2s[1][base + j];
        }
    }
    #pragma unroll
    for (int o = 4; o >= 1; o >>= 1) {
        a0 += __shfl_down(a0, o, 8);
        a1 += __shfl_down(a1, o, 8);
    }
    if (sub == 0) {
        out[row * 2]      = a0 + b2[0];
        out[row * 2 + 1]  = a1 + b2[1];
        // rel_BN: softmax rows sum to 1 -> mean over Lt = 1/32, mean over H = 1/32
        out[100352 + row] = 0.03125f;
    }
}

extern "C" void kernel_launch(void* const* d_in, const int* in_sizes, int n_in,
                              void* d_out, int out_size, void* d_ws, size_t ws_size,
                              hipStream_t stream) {
    const float* vis = (const float*)d_in[0];
    const float* txt = (const float*)d_in[1];
    const float* Wq  = (const float*)d_in[2];
    const float* bq  = (const float*)d_in[3];
    const float* Wk  = (const float*)d_in[4];
    const float* bk  = (const float*)d_in[5];
    const float* Wv  = (const float*)d_in[6];
    const float* bv  = (const float*)d_in[7];
    const float* W1  = (const float*)d_in[8];
    const float* b1  = (const float*)d_in[9];
    const float* W2  = (const float*)d_in[10];
    const float* b2  = (const float*)d_in[11];
    float* out = (float*)d_out;

    char* w = (char*)d_ws;
    unsigned short* Abf = (unsigned short*)(w);              // 77,070,336 B (vis bf16; becomes "fused")
    unsigned short* Tbf = (unsigned short*)(w + 77070336);   //  8,388,608 B (text bf16)
    unsigned short* Wqt = (unsigned short*)(w + 85458944);   //  1,179,648 B
    unsigned short* Wkt = (unsigned short*)(w + 86638592);   //    786,432 B
    unsigned short* Wvt = (unsigned short*)(w + 87425024);   //    786,432 B
    unsigned short* W1t = (unsigned short*)(w + 88211456);   //  1,179,648 B
    unsigned short* Qbf = (unsigned short*)(w + 89391104);   // 77,070,336 B (Q; reused as H after attn)
    unsigned short* Kbf = (unsigned short*)(w + 166461440);  // 12,582,912 B
    unsigned short* Vbf = (unsigned short*)(w + 179044352);  // 12,582,912 B
    unsigned short* Hbf = Qbf;  // Q dead after attention

    // 9,633,792 + 1,048,576 float4s = 41,728 blocks exactly
    cvt2_kernel<<<41728, 256, 0, stream>>>(vis, Abf, 9633792, txt, Tbf);
    // 576 + 384 + 384 + 576 = 1,920 blocks
    transpose4_kernel<<<1920, 256, 0, stream>>>(Wq, Wqt, Wk, Wkt, Wv, Wvt, W1, W1t);

    gemm_db_kernel<768, 0, 392><<<2352, 256, 0, stream>>>(Abf, Wqt, bq, Qbf);
    gemm_kv_kernel<512, 64><<<768, 256, 0, stream>>>(Tbf, Wkt, bk, Kbf, Wvt, bv, Vbf);

    attn_mfma_kernel<<<3072, 256, 0, stream>>>(Qbf, Kbf, Vbf, Abf);

    gemm_db_kernel<768, 1, 392><<<2352, 256, 0, stream>>>(Abf, W1t, b1, Hbf);

    mlp2_kernel<<<1568, 256, 0, stream>>>(Hbf, W2, b2, out);
}

// Round 4
// 488.726 us; speedup vs baseline: 1.1464x; 1.0461x over previous
//
#include <hip/hip_runtime.h>
#include <hip/hip_bf16.h>

// Dims: B=256, Nv=196, Lt=32, Ci=768, Ct=512, H=12, D=64
// M1 = 50176 (=392*128), M2 = 8192 (=64*128), N = 768 (=6*128)

typedef __attribute__((ext_vector_type(8))) short bf16x8;
typedef __attribute__((ext_vector_type(4))) float f32x4;

__device__ __forceinline__ float bf2f(unsigned short u) {
    return __uint_as_float(((unsigned int)u) << 16);
}
__device__ __forceinline__ unsigned short f2bf(float f) {
    unsigned int x = __float_as_uint(f);
    unsigned int r = (x + 0x7FFFu + ((x >> 16) & 1u)) >> 16;  // RNE
    return (unsigned short)r;
}

// async global->LDS, 16B/lane. LDS dest is wave-uniform base + lane*16.
#define GLOAD_LDS16(gp, lp)                                                    \
    __builtin_amdgcn_global_load_lds(                                          \
        (__attribute__((address_space(1))) void*)(gp),                         \
        (__attribute__((address_space(3))) void*)(lp), 16, 0, 0)

// ---------------- fp32 -> bf16 convert (both tensors, one launch) ----------
__global__ void cvt2_kernel(const float* __restrict__ in0,
                            unsigned short* __restrict__ out0, int n0,
                            const float* __restrict__ in1,
                            unsigned short* __restrict__ out1) {
    int i = blockIdx.x * 256 + threadIdx.x;
    const float* in = in0; unsigned short* out = out0;
    if (i >= n0) { i -= n0; in = in1; out = out1; }
    float4 v = ((const float4*)in)[i];
    ushort4 o;
    o.x = f2bf(v.x); o.y = f2bf(v.y); o.z = f2bf(v.z); o.w = f2bf(v.w);
    ((ushort4*)out)[i] = o;
}

// ---------------- all four W[K][N] -> Wt[N][K] transposes, one launch ------
__global__ void transpose4_kernel(const float* __restrict__ Wq, unsigned short* __restrict__ Wqt,
                                  const float* __restrict__ Wk, unsigned short* __restrict__ Wkt,
                                  const float* __restrict__ Wv, unsigned short* __restrict__ Wvt,
                                  const float* __restrict__ W1, unsigned short* __restrict__ W1t) {
    __shared__ float tile[32][33];
    int id = blockIdx.x;
    const float* W; unsigned short* Wt; int K;
    if (id < 576)       { W = Wq; Wt = Wqt; K = 768; }
    else if (id < 960)  { id -= 576;  W = Wk; Wt = Wkt; K = 512; }
    else if (id < 1344) { id -= 960;  W = Wv; Wt = Wvt; K = 512; }
    else                { id -= 1344; W = W1; Wt = W1t; K = 768; }
    int n0 = (id % 24) * 32, k0 = (id / 24) * 32;
    int tx = threadIdx.x & 31, ty = threadIdx.x >> 5;  // 256 thr: ty 0..7
    #pragma unroll
    for (int r = ty; r < 32; r += 8)
        tile[r][tx] = W[(size_t)(k0 + r) * 768 + n0 + tx];
    __syncthreads();
    #pragma unroll
    for (int r = ty; r < 32; r += 8)
        Wt[(size_t)(n0 + r) * K + k0 + tx] = f2bf(tile[tx][r]);
}

// ---------------- 128x128 bf16 MFMA GEMM (m97 2-phase, proven schedule) ----
// Schedule = round-0's proven 87us structure verbatim: single LDS buffer,
// STG(t) -> __syncthreads (drains vmcnt0) -> COMPUTE -> __syncthreads.
// Latency hiding comes from 4-5 resident blocks/CU (m114 implicit overlap);
// R3 showed explicit dbuf/counted-vmcnt REGRESSES this structure (m99/m100).
// Layout = R2/R3-validated zero-conflict st_16x32: per K-tile 2 k-panels
// [128 rows][32 bf16] (row stride 64B); swizzle slot-bit1 ^= row-bit3.
// Staging: linear LDS dest (global_load_lds), inverse-swizzled per-lane
// GLOBAL source (exact involution of the read-side XOR). Conflicts == 0.
// Epilogue: j-innermost so each row's 128B C-line completes in 4 stores
// (WRITE_SIZE ideal 75MB, validated R2/R3).
// Occupancy: 32KB LDS + ~64 VGPR -> 4-5 blocks/CU with launch_bounds(256,4).
template<int KTOT, int GELU, int MTILES>
__device__ __forceinline__
void gemm_body(int id, const unsigned short* __restrict__ A,
               const unsigned short* __restrict__ Bt,
               const float* __restrict__ bias,
               unsigned short* __restrict__ C,
               unsigned short* As, unsigned short* Bs) {
    constexpr int NT = KTOT / 64;
    constexpr int PAN = 4096;          // 128 rows x 32 shorts (one k-panel)
    const int tid = threadIdx.x;
    const int lane = tid & 63, wave = tid >> 6;        // 4 waves, 2x2
    const int wm = (wave >> 1) * 64, wn = (wave & 1) * 64;
    const int lr = lane & 15, quad = lane >> 4;

    // XCD-chunked tile mapping (grid % 8 == 0 for all uses)
    const int xcd = id & 7, local = id >> 3;
    const int nt = local % 6, mt = xcd * (MTILES / 8) + local / 6;
    const size_t m0 = (size_t)mt * 128;
    const int n0 = nt * 128;

    // read-side swizzled addressing (row*32 shorts + XORed 8-short slot)
    const int slotoff = ((quad ^ (((lr >> 3) & 1) << 1)) << 3);
    const int aBase = (wm + lr) * 32 + slotoff;        // + i*512 + kk*PAN
    const int bBase = (wn + lr) * 32 + slotoff;

    // staging source (pre-swizzled global): lane -> row lane>>2, slot
    // (lane&3)^(((lane>>5)&1)<<1); LDS dest linear -> slot s of row r holds
    // global chunk s ^ ((r&8)?2:0), matching the read-side XOR (involution).
    const int sg = (lane & 3) ^ (((lane >> 5) & 1) << 1);
    const unsigned short* gA = A + (m0 + (lane >> 2)) * (size_t)KTOT + sg * 8;
    const unsigned short* gB = Bt + ((size_t)n0 + (lane >> 2)) * KTOT + sg * 8;
    const int sr = wave * 32;   // wave's 32-row strip (2 x 16-row blocks)

    f32x4 acc[4][4] = {};

    for (int t = 0; t < NT; ++t) {
        #pragma unroll
        for (int p = 0; p < 2; ++p) {
            #pragma unroll
            for (int q = 0; q < 2; ++q) {
                const int r0 = sr + q * 16;
                GLOAD_LDS16(gA + (size_t)r0 * KTOT + t * 64 + p * 32,
                            As + p * PAN + r0 * 32);
                GLOAD_LDS16(gB + (size_t)r0 * KTOT + t * 64 + p * 32,
                            Bs + p * PAN + r0 * 32);
            }
        }
        __syncthreads();   // compiler drains vmcnt(0) before barrier
        #pragma unroll
        for (int kk = 0; kk < 2; ++kk) {
            bf16x8 fa[4], fb[4];
            #pragma unroll
            for (int i = 0; i < 4; ++i)
                fa[i] = *(const bf16x8*)(As + kk * PAN + aBase + i * 512);
            #pragma unroll
            for (int j = 0; j < 4; ++j)
                fb[j] = *(const bf16x8*)(Bs + kk * PAN + bBase + j * 512);
            #pragma unroll
            for (int i = 0; i < 4; ++i)
                #pragma unroll
                for (int j = 0; j < 4; ++j)
                    acc[i][j] = __builtin_amdgcn_mfma_f32_16x16x32_bf16(
                        fa[i], fb[j], acc[i][j], 0, 0, 0);
        }
        __syncthreads();
    }

    // epilogue: C/D layout col=lane&15, row=quad*4+reg [m89-verified];
    // j innermost so each row's 128B span completes in 4 consecutive stores.
    float bvv[4];
    #pragma unroll
    for (int j = 0; j < 4; ++j)
        bvv[j] = bias[n0 + wn + j * 16 + lr];
    #pragma unroll
    for (int i = 0; i < 4; ++i) {
        #pragma unroll
        for (int r2 = 0; r2 < 4; ++r2) {
            size_t row = m0 + wm + i * 16 + quad * 4 + r2;
            unsigned short* cp = C + row * 768 + n0 + wn + lr;
            #pragma unroll
            for (int j = 0; j < 4; ++j) {
                float x = acc[i][j][r2] + bvv[j];
                if (GELU) x = x / (1.0f + __expf(-1.702f * x));  // quick_gelu
                cp[j * 16] = f2bf(x);
            }
        }
    }
}

template<int KTOT, int GELU, int MTILES>
__global__ __launch_bounds__(256, 4)
void gemm_db_kernel(const unsigned short* __restrict__ A,
                    const unsigned short* __restrict__ Bt,
                    const float* __restrict__ bias,
                    unsigned short* __restrict__ C) {
    __shared__ unsigned short As[2 * 4096];   // 16 KB
    __shared__ unsigned short Bs[2 * 4096];   // 16 KB
    gemm_body<KTOT, GELU, MTILES>(blockIdx.x, A, Bt, bias, C, As, Bs);
}

// K and V projections in ONE dispatch (share A=Tbf in L2)
template<int KTOT, int MTILES>
__global__ __launch_bounds__(256, 4)
void gemm_kv_kernel(const unsigned short* __restrict__ A,
                    const unsigned short* __restrict__ Bt0,
                    const float* __restrict__ bias0,
                    unsigned short* __restrict__ C0,
                    const unsigned short* __restrict__ Bt1,
                    const float* __restrict__ bias1,
                    unsigned short* __restrict__ C1) {
    __shared__ unsigned short As[2 * 4096];
    __shared__ unsigned short Bs[2 * 4096];
    const int half = gridDim.x >> 1;
    if (blockIdx.x < half)
        gemm_body<KTOT, 0, MTILES>(blockIdx.x, A, Bt0, bias0, C0, As, Bs);
    else
        gemm_body<KTOT, 0, MTILES>(blockIdx.x - half, A, Bt1, bias1, C1, As, Bs);
}

// ---------------- MFMA attention: one block per (b,h), 4 waves -------------
__global__ __launch_bounds__(256, 4)
void attn_mfma_kernel(const unsigned short* __restrict__ Q,
                      const unsigned short* __restrict__ Kb,
                      const unsigned short* __restrict__ Vb,
                      unsigned short* __restrict__ RF) {
    constexpr int KS = 72;  // Ks row stride
    constexpr int VS = 34;  // Vt row stride
    constexpr int PS = 40;  // P row stride
    constexpr int CS = 72;  // ctx row stride
    __shared__ unsigned short Ks[32 * KS];      // K rows  [l][d]
    __shared__ unsigned short Vt[64 * VS];      // V^T     [d][l]
    __shared__ unsigned short Pb[4][16 * PS];   // per-wave P  [m][l]
    __shared__ unsigned short Cb[4][16 * CS];   // per-wave ctx[m][d]
    const int tid = threadIdx.x;
    const int b = blockIdx.x / 12, h = blockIdx.x % 12;
    const int lane = tid & 63, wave = tid >> 6;
    const int lr = lane & 15, quad = lane >> 4;

    {   // stage K rows + V transposed (bf16, one-time)
        int l = tid >> 3, d8 = (tid & 7) * 8;
        size_t base = ((size_t)b * 32 + l) * 768 + (size_t)h * 64 + d8;
        bf16x8 kv = *(const bf16x8*)(Kb + base);
        bf16x8 vv = *(const bf16x8*)(Vb + base);
        *(bf16x8*)(Ks + l * KS + d8) = kv;
        #pragma unroll
        for (int j = 0; j < 8; ++j)
            Vt[(d8 + j) * VS + l] = (unsigned short)vv[j];
    }
    __syncthreads();

    bf16x8 fbK[2][2];
    #pragma unroll
    for (int n = 0; n < 2; ++n)
        #pragma unroll
        for (int ks = 0; ks < 2; ++ks)
            fbK[n][ks] = *(const bf16x8*)(Ks + (n * 16 + lr) * KS + ks * 32 + quad * 8);
    bf16x8 fbV[4];
    #pragma unroll
    for (int d = 0; d < 4; ++d)
        fbV[d] = *(const bf16x8*)(Vt + (d * 16 + lr) * VS + quad * 8);

    const size_t qbase = (size_t)b * 196 * 768 + (size_t)h * 64;

    for (int t = wave; t < 13; t += 4) {   // 13 tiles of 16 rows cover 196
        const int m0 = t * 16;
        int qrow = m0 + lr; if (qrow > 195) qrow = 195;  // clamp tail dups
        const unsigned short* qp = Q + qbase + (size_t)qrow * 768;
        bf16x8 fa0 = *(const bf16x8*)(qp + quad * 8);
        bf16x8 fa1 = *(const bf16x8*)(qp + 32 + quad * 8);

        // T14 issue-early: prefetch residual rows now, consumed at tile end.
        // Safe: this wave exclusively owns rows [m0,m0+16) x this head's 64
        // cols, and writes them only at the end of THIS iteration.
        bf16x8 rv[2]; int rrow[2];
        #pragma unroll
        for (int i = 0; i < 2; ++i) {
            int c2 = lane + i * 64;
            rrow[i] = m0 + (c2 >> 3);
            if (rrow[i] < 196)
                rv[i] = *(const bf16x8*)(RF + qbase + (size_t)rrow[i] * 768 +
                                         (c2 & 7) * 8);
        }

        f32x4 s0 = {}, s1 = {};
        s0 = __builtin_amdgcn_mfma_f32_16x16x32_bf16(fa0, fbK[0][0], s0, 0, 0, 0);
        s0 = __builtin_amdgcn_mfma_f32_16x16x32_bf16(fa1, fbK[0][1], s0, 0, 0, 0);
        s1 = __builtin_amdgcn_mfma_f32_16x16x32_bf16(fa0, fbK[1][0], s1, 0, 0, 0);
        s1 = __builtin_amdgcn_mfma_f32_16x16x32_bf16(fa1, fbK[1][1], s1, 0, 0, 0);

        float p0[4], p1[4], m4[4], s4[4];
        #pragma unroll
        for (int r = 0; r < 4; ++r) {
            p0[r] = s0[r] * 0.125f;
            p1[r] = s1[r] * 0.125f;
            m4[r] = fmaxf(p0[r], p1[r]);
        }
        #pragma unroll
        for (int off = 1; off < 16; off <<= 1)
            #pragma unroll
            for (int r = 0; r < 4; ++r)
                m4[r] = fmaxf(m4[r], __shfl_xor(m4[r], off));
        #pragma unroll
        for (int r = 0; r < 4; ++r) {
            p0[r] = __expf(p0[r] - m4[r]);
            p1[r] = __expf(p1[r] - m4[r]);
            s4[r] = p0[r] + p1[r];
        }
        #pragma unroll
        for (int off = 1; off < 16; off <<= 1)
            #pragma unroll
            for (int r = 0; r < 4; ++r)
                s4[r] += __shfl_xor(s4[r], off);
        #pragma unroll
        for (int r = 0; r < 4; ++r) {
            float inv = __builtin_amdgcn_rcpf(s4[r]);
            unsigned short* pr = &Pb[wave][(quad * 4 + r) * PS];
            pr[lr]      = f2bf(p0[r] * inv);
            pr[16 + lr] = f2bf(p1[r] * inv);
        }

        bf16x8 fap = *(const bf16x8*)(&Pb[wave][lr * PS + quad * 8]);
        f32x4 c[4];
        #pragma unroll
        for (int d = 0; d < 4; ++d) {
            f32x4 z = {};
            c[d] = __builtin_amdgcn_mfma_f32_16x16x32_bf16(fap, fbV[d], z, 0, 0, 0);
        }
        #pragma unroll
        for (int d = 0; d < 4; ++d)
            #pragma unroll
            for (int r = 0; r < 4; ++r)
                Cb[wave][(quad * 4 + r) * CS + d * 16 + lr] = f2bf(c[d][r]);
        #pragma unroll
        for (int i = 0; i < 2; ++i) {
            int c2 = lane + i * 64;
            int row = c2 >> 3, col8 = (c2 & 7) * 8;
            if (rrow[i] < 196) {
                bf16x8 cv = *(const bf16x8*)(&Cb[wave][row * CS + col8]);
                unsigned short* gp = RF + qbase + (size_t)rrow[i] * 768 + col8;
                bf16x8 ov;
                #pragma unroll
                for (int j = 0; j < 8; ++j)
                    ov[j] = (short)f2bf(bf2f((unsigned short)cv[j]) +
                                        bf2f((unsigned short)rv[i][j]));
                *(bf16x8*)gp = ov;
            }
        }
    }
}

// ---------------- MLP2: logits[m][0..1] = h[m] . W2 + b2 ; rel fill --------
__global__ __launch_bounds__(256)
void mlp2_kernel(const unsigned short* __restrict__ Hb,
                 const float* __restrict__ W2,   // [768][2]
                 const float* __restrict__ b2,
                 float* __restrict__ out) {
    __shared__ float w2s[2][768];
    const int tid = threadIdx.x;
    for (int i = tid; i < 1536; i += 256) w2s[i & 1][i >> 1] = W2[i];
    __syncthreads();
    const int sub = tid & 7;
    const int r = tid >> 3;                       // 0..31 rows per block
    const size_t row = (size_t)blockIdx.x * 32 + r;
    float a0 = 0.f, a1 = 0.f;
    #pragma unroll
    for (int i = 0; i < 12; ++i) {
        int base = i * 64 + sub * 8;
        bf16x8 hv = *(const bf16x8*)(Hb + row * 768 + base);
        #pragma unroll
        for (int j = 0; j < 8; ++j) {
            float hf = bf2f((unsigned short)hv[j]);
            a0 += hf * w2s[0][base + j];
            a1 += hf * w2s[1][base + j];
        }
    }
    #pragma unroll
    for (int o = 4; o >= 1; o >>= 1) {
        a0 += __shfl_down(a0, o, 8);
        a1 += __shfl_down(a1, o, 8);
    }
    if (sub == 0) {
        out[row * 2]      = a0 + b2[0];
        out[row * 2 + 1]  = a1 + b2[1];
        // rel_BN: softmax rows sum to 1 -> mean over Lt = 1/32, mean over H = 1/32
        out[100352 + row] = 0.03125f;
    }
}

extern "C" void kernel_launch(void* const* d_in, const int* in_sizes, int n_in,
                              void* d_out, int out_size, void* d_ws, size_t ws_size,
                              hipStream_t stream) {
    const float* vis = (const float*)d_in[0];
    const float* txt = (const float*)d_in[1];
    const float* Wq  = (const float*)d_in[2];
    const float* bq  = (const float*)d_in[3];
    const float* Wk  = (const float*)d_in[4];
    const float* bk  = (const float*)d_in[5];
    const float* Wv  = (const float*)d_in[6];
    const float* bv  = (const float*)d_in[7];
    const float* W1  = (const float*)d_in[8];
    const float* b1  = (const float*)d_in[9];
    const float* W2  = (const float*)d_in[10];
    const float* b2  = (const float*)d_in[11];
    float* out = (float*)d_out;

    char* w = (char*)d_ws;
    unsigned short* Abf = (unsigned short*)(w);              // 77,070,336 B (vis bf16; becomes "fused")
    unsigned short* Tbf = (unsigned short*)(w + 77070336);   //  8,388,608 B (text bf16)
    unsigned short* Wqt = (unsigned short*)(w + 85458944);   //  1,179,648 B
    unsigned short* Wkt = (unsigned short*)(w + 86638592);   //    786,432 B
    unsigned short* Wvt = (unsigned short*)(w + 87425024);   //    786,432 B
    unsigned short* W1t = (unsigned short*)(w + 88211456);   //  1,179,648 B
    unsigned short* Qbf = (unsigned short*)(w + 89391104);   // 77,070,336 B (Q; reused as H after attn)
    unsigned short* Kbf = (unsigned short*)(w + 166461440);  // 12,582,912 B
    unsigned short* Vbf = (unsigned short*)(w + 179044352);  // 12,582,912 B
    unsigned short* Hbf = Qbf;  // Q dead after attention

    // 9,633,792 + 1,048,576 float4s = 41,728 blocks exactly
    cvt2_kernel<<<41728, 256, 0, stream>>>(vis, Abf, 9633792, txt, Tbf);
    // 576 + 384 + 384 + 576 = 1,920 blocks
    transpose4_kernel<<<1920, 256, 0, stream>>>(Wq, Wqt, Wk, Wkt, Wv, Wvt, W1, W1t);

    gemm_db_kernel<768, 0, 392><<<2352, 256, 0, stream>>>(Abf, Wqt, bq, Qbf);
    gemm_kv_kernel<512, 64><<<768, 256, 0, stream>>>(Tbf, Wkt, bk, Kbf, Wvt, bv, Vbf);

    attn_mfma_kernel<<<3072, 256, 0, stream>>>(Qbf, Kbf, Vbf, Abf);

    gemm_db_kernel<768, 1, 392><<<2352, 256, 0, stream>>>(Abf, W1t, b1, Hbf);

    mlp2_kernel<<<1568, 256, 0, stream>>>(Hbf, W2, b2, out);
}

// Round 5
// 482.397 us; speedup vs baseline: 1.1615x; 1.0131x over previous
//
#include <hip/hip_runtime.h>
#include <hip/hip_bf16.h>

// Dims: B=256, Nv=196, Lt=32, Ci=768, Ct=512, H=12, D=64
// M1 = 50176 (=392*128), M2 = 8192 (=64*128), N = 768 (=6*128)

typedef __attribute__((ext_vector_type(8))) short bf16x8;
typedef __attribute__((ext_vector_type(4))) float f32x4;

__device__ __forceinline__ float bf2f(unsigned short u) {
    return __uint_as_float(((unsigned int)u) << 16);
}
__device__ __forceinline__ unsigned short f2bf(float f) {
    unsigned int x = __float_as_uint(f);
    unsigned int r = (x + 0x7FFFu + ((x >> 16) & 1u)) >> 16;  // RNE
    return (unsigned short)r;
}

// async global->LDS, 16B/lane. LDS dest is wave-uniform base + lane*16.
#define GLOAD_LDS16(gp, lp)                                                    \
    __builtin_amdgcn_global_load_lds(                                          \
        (__attribute__((address_space(1))) void*)(gp),                         \
        (__attribute__((address_space(3))) void*)(lp), 16, 0, 0)

// ---------------- fp32 -> bf16 convert (both tensors, one launch) ----------
__global__ void cvt2_kernel(const float* __restrict__ in0,
                            unsigned short* __restrict__ out0, int n0,
                            const float* __restrict__ in1,
                            unsigned short* __restrict__ out1) {
    int i = blockIdx.x * 256 + threadIdx.x;
    const float* in = in0; unsigned short* out = out0;
    if (i >= n0) { i -= n0; in = in1; out = out1; }
    float4 v = ((const float4*)in)[i];
    ushort4 o;
    o.x = f2bf(v.x); o.y = f2bf(v.y); o.z = f2bf(v.z); o.w = f2bf(v.w);
    ((ushort4*)out)[i] = o;
}

// -------- all four W[K][N] -> Wt[N][K] transposes + out-init, one launch ---
// blocks 0..1919: transposes; blocks 1920..2507: init logits=b2, rel=1/32
// (logits are accumulated via atomicAdd by the fused GELU+mlp2 epilogue).
__global__ void transpose4_kernel(const float* __restrict__ Wq, unsigned short* __restrict__ Wqt,
                                  const float* __restrict__ Wk, unsigned short* __restrict__ Wkt,
                                  const float* __restrict__ Wv, unsigned short* __restrict__ Wvt,
                                  const float* __restrict__ W1, unsigned short* __restrict__ W1t,
                                  const float* __restrict__ b2, float* __restrict__ out) {
    int id = blockIdx.x;
    if (id >= 1920) {   // 588 blocks x 256 = 150528 = 100352 logits + 50176 rel
        int idx = (id - 1920) * 256 + threadIdx.x;
        out[idx] = (idx < 100352) ? b2[idx & 1] : 0.03125f;
        return;
    }
    __shared__ float tile[32][33];
    const float* W; unsigned short* Wt; int K;
    if (id < 576)       { W = Wq; Wt = Wqt; K = 768; }
    else if (id < 960)  { id -= 576;  W = Wk; Wt = Wkt; K = 512; }
    else if (id < 1344) { id -= 960;  W = Wv; Wt = Wvt; K = 512; }
    else                { id -= 1344; W = W1; Wt = W1t; K = 768; }
    int n0 = (id % 24) * 32, k0 = (id / 24) * 32;
    int tx = threadIdx.x & 31, ty = threadIdx.x >> 5;  // 256 thr: ty 0..7
    #pragma unroll
    for (int r = ty; r < 32; r += 8)
        tile[r][tx] = W[(size_t)(k0 + r) * 768 + n0 + tx];
    __syncthreads();
    #pragma unroll
    for (int r = ty; r < 32; r += 8)
        Wt[(size_t)(n0 + r) * K + k0 + tx] = f2bf(tile[tx][r]);
}

// ---------------- 128x128 bf16 MFMA GEMM (m97 2-phase, proven schedule) ----
// Loop structure byte-identical to R4 (91us, occupancy 30%, conflicts 0):
// single LDS buffer, STG -> __syncthreads -> COMPUTE -> __syncthreads;
// zero-conflict st_16x32 panel layout; 4-5 blocks/CU latency hiding (m114).
// R0-R4 established: conflicts/stores/dbuf/8-phase all don't move this
// structure's loop time -> this round touches ONLY the epilogue + launches.
// GELU=1: fused mlp2 -- logits partials reduced in-register (fp32 h, more
// accurate than the old bf16 Hbf round-trip) and atomicAdd'd to out;
// the 75MB C-write and mlp2's 77MB re-read are eliminated.
template<int KTOT, int GELU, int MTILES>
__device__ __forceinline__
void gemm_body(int id, const unsigned short* __restrict__ A,
               const unsigned short* __restrict__ Bt,
               const float* __restrict__ bias,
               unsigned short* __restrict__ C,
               const float* __restrict__ W2,
               float* __restrict__ out2,
               unsigned short* As, unsigned short* Bs) {
    constexpr int NT = KTOT / 64;
    constexpr int PAN = 4096;          // 128 rows x 32 shorts (one k-panel)
    const int tid = threadIdx.x;
    const int lane = tid & 63, wave = tid >> 6;        // 4 waves, 2x2
    const int wm = (wave >> 1) * 64, wn = (wave & 1) * 64;
    const int lr = lane & 15, quad = lane >> 4;

    // XCD-chunked tile mapping (grid % 8 == 0 for all uses)
    const int xcd = id & 7, local = id >> 3;
    const int nt = local % 6, mt = xcd * (MTILES / 8) + local / 6;
    const size_t m0 = (size_t)mt * 128;
    const int n0 = nt * 128;

    // read-side swizzled addressing (row*32 shorts + XORed 8-short slot)
    const int slotoff = ((quad ^ (((lr >> 3) & 1) << 1)) << 3);
    const int aBase = (wm + lr) * 32 + slotoff;        // + i*512 + kk*PAN
    const int bBase = (wn + lr) * 32 + slotoff;

    // staging source (pre-swizzled global): lane -> row lane>>2, slot
    // (lane&3)^(((lane>>5)&1)<<1); LDS dest linear; involution of read XOR.
    const int sg = (lane & 3) ^ (((lane >> 5) & 1) << 1);
    const unsigned short* gA = A + (m0 + (lane >> 2)) * (size_t)KTOT + sg * 8;
    const unsigned short* gB = Bt + ((size_t)n0 + (lane >> 2)) * KTOT + sg * 8;
    const int sr = wave * 32;   // wave's 32-row strip (2 x 16-row blocks)

    f32x4 acc[4][4] = {};

    for (int t = 0; t < NT; ++t) {
        #pragma unroll
        for (int p = 0; p < 2; ++p) {
            #pragma unroll
            for (int q = 0; q < 2; ++q) {
                const int r0 = sr + q * 16;
                GLOAD_LDS16(gA + (size_t)r0 * KTOT + t * 64 + p * 32,
                            As + p * PAN + r0 * 32);
                GLOAD_LDS16(gB + (size_t)r0 * KTOT + t * 64 + p * 32,
                            Bs + p * PAN + r0 * 32);
            }
        }
        __syncthreads();   // compiler drains vmcnt(0) before barrier
        #pragma unroll
        for (int kk = 0; kk < 2; ++kk) {
            bf16x8 fa[4], fb[4];
            #pragma unroll
            for (int i = 0; i < 4; ++i)
                fa[i] = *(const bf16x8*)(As + kk * PAN + aBase + i * 512);
            #pragma unroll
            for (int j = 0; j < 4; ++j)
                fb[j] = *(const bf16x8*)(Bs + kk * PAN + bBase + j * 512);
            #pragma unroll
            for (int i = 0; i < 4; ++i)
                #pragma unroll
                for (int j = 0; j < 4; ++j)
                    acc[i][j] = __builtin_amdgcn_mfma_f32_16x16x32_bf16(
                        fa[i], fb[j], acc[i][j], 0, 0, 0);
        }
        __syncthreads();
    }

    // epilogue: C/D layout col=lane&15, row=quad*4+reg [m89-verified]
    float bvv[4];
    #pragma unroll
    for (int j = 0; j < 4; ++j)
        bvv[j] = bias[n0 + wn + j * 16 + lr];

    if (GELU) {
        // fused mlp2: p{0,1} = sum_col gelu(h)*W2[col][{0,1}] over this
        // lane's 4 cols; butterfly over the 16-lane col group; atomicAdd.
        // 12 adders/address (2 wn-waves x 6 nt-blocks); out pre-init'd to b2.
        float w2a[4], w2b[4];
        #pragma unroll
        for (int j = 0; j < 4; ++j) {
            int col = n0 + wn + j * 16 + lr;
            w2a[j] = W2[col * 2];
            w2b[j] = W2[col * 2 + 1];
        }
        #pragma unroll
        for (int i = 0; i < 4; ++i) {
            #pragma unroll
            for (int r2 = 0; r2 < 4; ++r2) {
                size_t row = m0 + wm + i * 16 + quad * 4 + r2;
                float p0 = 0.f, p1 = 0.f;
                #pragma unroll
                for (int j = 0; j < 4; ++j) {
                    float x = acc[i][j][r2] + bvv[j];
                    x = x / (1.0f + __expf(-1.702f * x));  // quick_gelu
                    p0 += x * w2a[j];
                    p1 += x * w2b[j];
                }
                #pragma unroll
                for (int off = 1; off < 16; off <<= 1) {
                    p0 += __shfl_xor(p0, off);
                    p1 += __shfl_xor(p1, off);
                }
                if (lr == 0) {
                    atomicAdd(&out2[row * 2], p0);
                    atomicAdd(&out2[row * 2 + 1], p1);
                }
            }
        }
    } else {
        // j innermost: each row's 128B span completes in 4 consecutive stores
        #pragma unroll
        for (int i = 0; i < 4; ++i) {
            #pragma unroll
            for (int r2 = 0; r2 < 4; ++r2) {
                size_t row = m0 + wm + i * 16 + quad * 4 + r2;
                unsigned short* cp = C + row * 768 + n0 + wn + lr;
                #pragma unroll
                for (int j = 0; j < 4; ++j)
                    cp[j * 16] = f2bf(acc[i][j][r2] + bvv[j]);
            }
        }
    }
}

// Q, K and V projections in ONE dispatch (all inputs ready after cvt2+tr4).
// Sub-grids: [0,2352) Q (2352%8==0), [2352,2736) K, [2736,3120) V.
__global__ __launch_bounds__(256, 4)
void gemm_qkv_kernel(const unsigned short* __restrict__ Abf,
                     const unsigned short* __restrict__ Wqt,
                     const float* __restrict__ bq,
                     unsigned short* __restrict__ Qbf,
                     const unsigned short* __restrict__ Tbf,
                     const unsigned short* __restrict__ Wkt,
                     const float* __restrict__ bk,
                     unsigned short* __restrict__ Kbf,
                     const unsigned short* __restrict__ Wvt,
                     const float* __restrict__ bv,
                     unsigned short* __restrict__ Vbf) {
    __shared__ unsigned short As[2 * 4096];   // 16 KB
    __shared__ unsigned short Bs[2 * 4096];   // 16 KB
    const int id = blockIdx.x;
    if (id < 2352)
        gemm_body<768, 0, 392>(id, Abf, Wqt, bq, Qbf, nullptr, nullptr, As, Bs);
    else if (id < 2736)
        gemm_body<512, 0, 64>(id - 2352, Tbf, Wkt, bk, Kbf, nullptr, nullptr, As, Bs);
    else
        gemm_body<512, 0, 64>(id - 2736, Tbf, Wvt, bv, Vbf, nullptr, nullptr, As, Bs);
}

// GELU GEMM with fused mlp2 epilogue (no C output at all)
__global__ __launch_bounds__(256, 4)
void gemm_gelu_kernel(const unsigned short* __restrict__ A,
                      const unsigned short* __restrict__ Bt,
                      const float* __restrict__ bias,
                      const float* __restrict__ W2,
                      float* __restrict__ out) {
    __shared__ unsigned short As[2 * 4096];
    __shared__ unsigned short Bs[2 * 4096];
    gemm_body<768, 1, 392>(blockIdx.x, A, Bt, bias, nullptr, W2, out, As, Bs);
}

// ---------------- MFMA attention: one block per (b,h), 4 waves -------------
__global__ __launch_bounds__(256, 4)
void attn_mfma_kernel(const unsigned short* __restrict__ Q,
                      const unsigned short* __restrict__ Kb,
                      const unsigned short* __restrict__ Vb,
                      unsigned short* __restrict__ RF) {
    constexpr int KS = 72;  // Ks row stride
    constexpr int VS = 34;  // Vt row stride
    constexpr int PS = 40;  // P row stride
    constexpr int CS = 72;  // ctx row stride
    __shared__ unsigned short Ks[32 * KS];      // K rows  [l][d]
    __shared__ unsigned short Vt[64 * VS];      // V^T     [d][l]
    __shared__ unsigned short Pb[4][16 * PS];   // per-wave P  [m][l]
    __shared__ unsigned short Cb[4][16 * CS];   // per-wave ctx[m][d]
    const int tid = threadIdx.x;
    const int b = blockIdx.x / 12, h = blockIdx.x % 12;
    const int lane = tid & 63, wave = tid >> 6;
    const int lr = lane & 15, quad = lane >> 4;

    {   // stage K rows + V transposed (bf16, one-time)
        int l = tid >> 3, d8 = (tid & 7) * 8;
        size_t base = ((size_t)b * 32 + l) * 768 + (size_t)h * 64 + d8;
        bf16x8 kv = *(const bf16x8*)(Kb + base);
        bf16x8 vv = *(const bf16x8*)(Vb + base);
        *(bf16x8*)(Ks + l * KS + d8) = kv;
        #pragma unroll
        for (int j = 0; j < 8; ++j)
            Vt[(d8 + j) * VS + l] = (unsigned short)vv[j];
    }
    __syncthreads();

    bf16x8 fbK[2][2];
    #pragma unroll
    for (int n = 0; n < 2; ++n)
        #pragma unroll
        for (int ks = 0; ks < 2; ++ks)
            fbK[n][ks] = *(const bf16x8*)(Ks + (n * 16 + lr) * KS + ks * 32 + quad * 8);
    bf16x8 fbV[4];
    #pragma unroll
    for (int d = 0; d < 4; ++d)
        fbV[d] = *(const bf16x8*)(Vt + (d * 16 + lr) * VS + quad * 8);

    const size_t qbase = (size_t)b * 196 * 768 + (size_t)h * 64;

    for (int t = wave; t < 13; t += 4) {   // 13 tiles of 16 rows cover 196
        const int m0 = t * 16;
        int qrow = m0 + lr; if (qrow > 195) qrow = 195;  // clamp tail dups
        const unsigned short* qp = Q + qbase + (size_t)qrow * 768;
        bf16x8 fa0 = *(const bf16x8*)(qp + quad * 8);
        bf16x8 fa1 = *(const bf16x8*)(qp + 32 + quad * 8);

        // T14 issue-early: prefetch residual rows now, consumed at tile end.
        bf16x8 rv[2]; int rrow[2];
        #pragma unroll
        for (int i = 0; i < 2; ++i) {
            int c2 = lane + i * 64;
            rrow[i] = m0 + (c2 >> 3);
            if (rrow[i] < 196)
                rv[i] = *(const bf16x8*)(RF + qbase + (size_t)rrow[i] * 768 +
                                         (c2 & 7) * 8);
        }

        f32x4 s0 = {}, s1 = {};
        s0 = __builtin_amdgcn_mfma_f32_16x16x32_bf16(fa0, fbK[0][0], s0, 0, 0, 0);
        s0 = __builtin_amdgcn_mfma_f32_16x16x32_bf16(fa1, fbK[0][1], s0, 0, 0, 0);
        s1 = __builtin_amdgcn_mfma_f32_16x16x32_bf16(fa0, fbK[1][0], s1, 0, 0, 0);
        s1 = __builtin_amdgcn_mfma_f32_16x16x32_bf16(fa1, fbK[1][1], s1, 0, 0, 0);

        float p0[4], p1[4], m4[4], s4[4];
        #pragma unroll
        for (int r = 0; r < 4; ++r) {
            p0[r] = s0[r] * 0.125f;
            p1[r] = s1[r] * 0.125f;
            m4[r] = fmaxf(p0[r], p1[r]);
        }
        #pragma unroll
        for (int off = 1; off < 16; off <<= 1)
            #pragma unroll
            for (int r = 0; r < 4; ++r)
                m4[r] = fmaxf(m4[r], __shfl_xor(m4[r], off));
        #pragma unroll
        for (int r = 0; r < 4; ++r) {
            p0[r] = __expf(p0[r] - m4[r]);
            p1[r] = __expf(p1[r] - m4[r]);
            s4[r] = p0[r] + p1[r];
        }
        #pragma unroll
        for (int off = 1; off < 16; off <<= 1)
            #pragma unroll
            for (int r = 0; r < 4; ++r)
                s4[r] += __shfl_xor(s4[r], off);
        #pragma unroll
        for (int r = 0; r < 4; ++r) {
            float inv = __builtin_amdgcn_rcpf(s4[r]);
            unsigned short* pr = &Pb[wave][(quad * 4 + r) * PS];
            pr[lr]      = f2bf(p0[r] * inv);
            pr[16 + lr] = f2bf(p1[r] * inv);
        }

        bf16x8 fap = *(const bf16x8*)(&Pb[wave][lr * PS + quad * 8]);
        f32x4 c[4];
        #pragma unroll
        for (int d = 0; d < 4; ++d) {
            f32x4 z = {};
            c[d] = __builtin_amdgcn_mfma_f32_16x16x32_bf16(fap, fbV[d], z, 0, 0, 0);
        }
        #pragma unroll
        for (int d = 0; d < 4; ++d)
            #pragma unroll
            for (int r = 0; r < 4; ++r)
                Cb[wave][(quad * 4 + r) * CS + d * 16 + lr] = f2bf(c[d][r]);
        #pragma unroll
        for (int i = 0; i < 2; ++i) {
            int c2 = lane + i * 64;
            int row = c2 >> 3, col8 = (c2 & 7) * 8;
            if (rrow[i] < 196) {
                bf16x8 cv = *(const bf16x8*)(&Cb[wave][row * CS + col8]);
                unsigned short* gp = RF + qbase + (size_t)rrow[i] * 768 + col8;
                bf16x8 ov;
                #pragma unroll
                for (int j = 0; j < 8; ++j)
                    ov[j] = (short)f2bf(bf2f((unsigned short)cv[j]) +
                                        bf2f((unsigned short)rv[i][j]));
                *(bf16x8*)gp = ov;
            }
        }
    }
}

extern "C" void kernel_launch(void* const* d_in, const int* in_sizes, int n_in,
                              void* d_out, int out_size, void* d_ws, size_t ws_size,
                              hipStream_t stream) {
    const float* vis = (const float*)d_in[0];
    const float* txt = (const float*)d_in[1];
    const float* Wq  = (const float*)d_in[2];
    const float* bq  = (const float*)d_in[3];
    const float* Wk  = (const float*)d_in[4];
    const float* bk  = (const float*)d_in[5];
    const float* Wv  = (const float*)d_in[6];
    const float* bv  = (const float*)d_in[7];
    const float* W1  = (const float*)d_in[8];
    const float* b1  = (const float*)d_in[9];
    const float* W2  = (const float*)d_in[10];
    const float* b2  = (const float*)d_in[11];
    float* out = (float*)d_out;

    char* w = (char*)d_ws;
    unsigned short* Abf = (unsigned short*)(w);              // 77,070,336 B (vis bf16; becomes "fused")
    unsigned short* Tbf = (unsigned short*)(w + 77070336);   //  8,388,608 B (text bf16)
    unsigned short* Wqt = (unsigned short*)(w + 85458944);   //  1,179,648 B
    unsigned short* Wkt = (unsigned short*)(w + 86638592);   //    786,432 B
    unsigned short* Wvt = (unsigned short*)(w + 87425024);   //    786,432 B
    unsigned short* W1t = (unsigned short*)(w + 88211456);   //  1,179,648 B
    unsigned short* Qbf = (unsigned short*)(w + 89391104);   // 77,070,336 B
    unsigned short* Kbf = (unsigned short*)(w + 166461440);  // 12,582,912 B
    unsigned short* Vbf = (unsigned short*)(w + 179044352);  // 12,582,912 B

    // 9,633,792 + 1,048,576 float4s = 41,728 blocks exactly
    cvt2_kernel<<<41728, 256, 0, stream>>>(vis, Abf, 9633792, txt, Tbf);
    // 1,920 transpose blocks + 588 out-init blocks
    transpose4_kernel<<<2508, 256, 0, stream>>>(Wq, Wqt, Wk, Wkt, Wv, Wvt,
                                                W1, W1t, b2, out);

    gemm_qkv_kernel<<<3120, 256, 0, stream>>>(Abf, Wqt, bq, Qbf,
                                              Tbf, Wkt, bk, Kbf,
                                              Wvt, bv, Vbf);

    attn_mfma_kernel<<<3072, 256, 0, stream>>>(Qbf, Kbf, Vbf, Abf);

    // GELU GEMM with fused mlp2 reduction (atomicAdd into pre-init'd out)
    gemm_gelu_kernel<<<2352, 256, 0, stream>>>(Abf, W1t, b1, W2, out);
}

// Round 6
// 470.313 us; speedup vs baseline: 1.1913x; 1.0257x over previous
//
#include <hip/hip_runtime.h>
#include <hip/hip_bf16.h>

// Dims: B=256, Nv=196, Lt=32, Ci=768, Ct=512, H=12, D=64
// M1 = 50176 (=392*128), M2 = 8192 (=64*128), N = 768 (=6*128)

typedef __attribute__((ext_vector_type(8))) short bf16x8;
typedef __attribute__((ext_vector_type(4))) float f32x4;

__device__ __forceinline__ float bf2f(unsigned short u) {
    return __uint_as_float(((unsigned int)u) << 16);
}
__device__ __forceinline__ unsigned short f2bf(float f) {
    unsigned int x = __float_as_uint(f);
    unsigned int r = (x + 0x7FFFu + ((x >> 16) & 1u)) >> 16;  // RNE
    return (unsigned short)r;
}

// async global->LDS, 16B/lane. LDS dest is wave-uniform base + lane*16.
#define GLOAD_LDS16(gp, lp)                                                    \
    __builtin_amdgcn_global_load_lds(                                          \
        (__attribute__((address_space(1))) void*)(gp),                         \
        (__attribute__((address_space(3))) void*)(lp), 16, 0, 0)

// ---------------- fp32 -> bf16 convert (both tensors, one launch) ----------
__global__ void cvt2_kernel(const float* __restrict__ in0,
                            unsigned short* __restrict__ out0, int n0,
                            const float* __restrict__ in1,
                            unsigned short* __restrict__ out1) {
    int i = blockIdx.x * 256 + threadIdx.x;
    const float* in = in0; unsigned short* out = out0;
    if (i >= n0) { i -= n0; in = in1; out = out1; }
    float4 v = ((const float4*)in)[i];
    ushort4 o;
    o.x = f2bf(v.x); o.y = f2bf(v.y); o.z = f2bf(v.z); o.w = f2bf(v.w);
    ((ushort4*)out)[i] = o;
}

// ---------------- all four W[K][N] -> Wt[N][K] transposes, one launch ------
__global__ void transpose4_kernel(const float* __restrict__ Wq, unsigned short* __restrict__ Wqt,
                                  const float* __restrict__ Wk, unsigned short* __restrict__ Wkt,
                                  const float* __restrict__ Wv, unsigned short* __restrict__ Wvt,
                                  const float* __restrict__ W1, unsigned short* __restrict__ W1t) {
    __shared__ float tile[32][33];
    int id = blockIdx.x;
    const float* W; unsigned short* Wt; int K;
    if (id < 576)       { W = Wq; Wt = Wqt; K = 768; }
    else if (id < 960)  { id -= 576;  W = Wk; Wt = Wkt; K = 512; }
    else if (id < 1344) { id -= 960;  W = Wv; Wt = Wvt; K = 512; }
    else                { id -= 1344; W = W1; Wt = W1t; K = 768; }
    int n0 = (id % 24) * 32, k0 = (id / 24) * 32;
    int tx = threadIdx.x & 31, ty = threadIdx.x >> 5;  // 256 thr: ty 0..7
    #pragma unroll
    for (int r = ty; r < 32; r += 8)
        tile[r][tx] = W[(size_t)(k0 + r) * 768 + n0 + tx];
    __syncthreads();
    #pragma unroll
    for (int r = ty; r < 32; r += 8)
        Wt[(size_t)(n0 + r) * K + k0 + tx] = f2bf(tile[tx][r]);
}

// ---------------- 128x128 bf16 MFMA GEMM (m97 2-phase, proven schedule) ----
// Loop structure byte-identical to R4/R5 (91us core, occupancy 30%,
// conflicts 0): single LDS buffer, STG -> __syncthreads -> COMPUTE ->
// __syncthreads; zero-conflict st_16x32 panel layout; 4 blocks/CU (m114).
// GELU=1: fused mlp2 partials. R5 showed the atomicAdd path costs ~21us
// (1.2M contended device-scope RMWs, 12-way/address; WRITE_SIZE 37.6MB of
// atomic line writebacks). This round: RACE-FREE scratch stores instead --
// slot part[row*24 + nt*4 + wn*2 + {0,1}] is owned by exactly one wave.
// 4.8MB fire-and-forget stores; final 6x2-way sum in a tiny reduce kernel.
template<int KTOT, int GELU, int MTILES>
__device__ __forceinline__
void gemm_body(int id, const unsigned short* __restrict__ A,
               const unsigned short* __restrict__ Bt,
               const float* __restrict__ bias,
               unsigned short* __restrict__ C,
               const float* __restrict__ W2,
               float* __restrict__ part,
               unsigned short* As, unsigned short* Bs) {
    constexpr int NT = KTOT / 64;
    constexpr int PAN = 4096;          // 128 rows x 32 shorts (one k-panel)
    const int tid = threadIdx.x;
    const int lane = tid & 63, wave = tid >> 6;        // 4 waves, 2x2
    const int wm = (wave >> 1) * 64, wn = (wave & 1) * 64;
    const int lr = lane & 15, quad = lane >> 4;

    // XCD-chunked tile mapping (grid % 8 == 0 for all uses)
    const int xcd = id & 7, local = id >> 3;
    const int nt = local % 6, mt = xcd * (MTILES / 8) + local / 6;
    const size_t m0 = (size_t)mt * 128;
    const int n0 = nt * 128;

    // read-side swizzled addressing (row*32 shorts + XORed 8-short slot)
    const int slotoff = ((quad ^ (((lr >> 3) & 1) << 1)) << 3);
    const int aBase = (wm + lr) * 32 + slotoff;        // + i*512 + kk*PAN
    const int bBase = (wn + lr) * 32 + slotoff;

    // staging source (pre-swizzled global): lane -> row lane>>2, slot
    // (lane&3)^(((lane>>5)&1)<<1); LDS dest linear; involution of read XOR.
    const int sg = (lane & 3) ^ (((lane >> 5) & 1) << 1);
    const unsigned short* gA = A + (m0 + (lane >> 2)) * (size_t)KTOT + sg * 8;
    const unsigned short* gB = Bt + ((size_t)n0 + (lane >> 2)) * KTOT + sg * 8;
    const int sr = wave * 32;   // wave's 32-row strip (2 x 16-row blocks)

    f32x4 acc[4][4] = {};

    for (int t = 0; t < NT; ++t) {
        #pragma unroll
        for (int p = 0; p < 2; ++p) {
            #pragma unroll
            for (int q = 0; q < 2; ++q) {
                const int r0 = sr + q * 16;
                GLOAD_LDS16(gA + (size_t)r0 * KTOT + t * 64 + p * 32,
                            As + p * PAN + r0 * 32);
                GLOAD_LDS16(gB + (size_t)r0 * KTOT + t * 64 + p * 32,
                            Bs + p * PAN + r0 * 32);
            }
        }
        __syncthreads();   // compiler drains vmcnt(0) before barrier
        #pragma unroll
        for (int kk = 0; kk < 2; ++kk) {
            bf16x8 fa[4], fb[4];
            #pragma unroll
            for (int i = 0; i < 4; ++i)
                fa[i] = *(const bf16x8*)(As + kk * PAN + aBase + i * 512);
            #pragma unroll
            for (int j = 0; j < 4; ++j)
                fb[j] = *(const bf16x8*)(Bs + kk * PAN + bBase + j * 512);
            #pragma unroll
            for (int i = 0; i < 4; ++i)
                #pragma unroll
                for (int j = 0; j < 4; ++j)
                    acc[i][j] = __builtin_amdgcn_mfma_f32_16x16x32_bf16(
                        fa[i], fb[j], acc[i][j], 0, 0, 0);
        }
        __syncthreads();
    }

    // epilogue: C/D layout col=lane&15, row=quad*4+reg [m89-verified]
    float bvv[4];
    #pragma unroll
    for (int j = 0; j < 4; ++j)
        bvv[j] = bias[n0 + wn + j * 16 + lr];

    if (GELU) {
        // fused mlp2 partials: p{0,1} = sum over this wave's 64 cols of
        // gelu(h)*W2; butterfly over the 16-lane col group; race-free store.
        float w2a[4], w2b[4];
        #pragma unroll
        for (int j = 0; j < 4; ++j) {
            int col = n0 + wn + j * 16 + lr;
            w2a[j] = W2[col * 2];
            w2b[j] = W2[col * 2 + 1];
        }
        const int sbase = nt * 4 + (wave & 1) * 2;   // slot: nt(6) x wn(2) x 2
        #pragma unroll
        for (int i = 0; i < 4; ++i) {
            #pragma unroll
            for (int r2 = 0; r2 < 4; ++r2) {
                size_t row = m0 + wm + i * 16 + quad * 4 + r2;
                float p0 = 0.f, p1 = 0.f;
                #pragma unroll
                for (int j = 0; j < 4; ++j) {
                    float x = acc[i][j][r2] + bvv[j];
                    x = x / (1.0f + __expf(-1.702f * x));  // quick_gelu
                    p0 += x * w2a[j];
                    p1 += x * w2b[j];
                }
                #pragma unroll
                for (int off = 1; off < 16; off <<= 1) {
                    p0 += __shfl_xor(p0, off);
                    p1 += __shfl_xor(p1, off);
                }
                if (lr == 0) {
                    float* pp = part + row * 24 + sbase;
                    pp[0] = p0;
                    pp[1] = p1;
                }
            }
        }
    } else {
        // j innermost: each row's 128B span completes in 4 consecutive stores
        #pragma unroll
        for (int i = 0; i < 4; ++i) {
            #pragma unroll
            for (int r2 = 0; r2 < 4; ++r2) {
                size_t row = m0 + wm + i * 16 + quad * 4 + r2;
                unsigned short* cp = C + row * 768 + n0 + wn + lr;
                #pragma unroll
                for (int j = 0; j < 4; ++j)
                    cp[j * 16] = f2bf(acc[i][j][r2] + bvv[j]);
            }
        }
    }
}

// Q, K and V projections in ONE dispatch (all inputs ready after cvt2+tr4).
// Sub-grids: [0,2352) Q (2352%8==0), [2352,2736) K, [2736,3120) V.
__global__ __launch_bounds__(256, 4)
void gemm_qkv_kernel(const unsigned short* __restrict__ Abf,
                     const unsigned short* __restrict__ Wqt,
                     const float* __restrict__ bq,
                     unsigned short* __restrict__ Qbf,
                     const unsigned short* __restrict__ Tbf,
                     const unsigned short* __restrict__ Wkt,
                     const float* __restrict__ bk,
                     unsigned short* __restrict__ Kbf,
                     const unsigned short* __restrict__ Wvt,
                     const float* __restrict__ bv,
                     unsigned short* __restrict__ Vbf) {
    __shared__ unsigned short As[2 * 4096];   // 16 KB
    __shared__ unsigned short Bs[2 * 4096];   // 16 KB
    const int id = blockIdx.x;
    if (id < 2352)
        gemm_body<768, 0, 392>(id, Abf, Wqt, bq, Qbf, nullptr, nullptr, As, Bs);
    else if (id < 2736)
        gemm_body<512, 0, 64>(id - 2352, Tbf, Wkt, bk, Kbf, nullptr, nullptr, As, Bs);
    else
        gemm_body<512, 0, 64>(id - 2736, Tbf, Wvt, bv, Vbf, nullptr, nullptr, As, Bs);
}

// GELU GEMM with fused mlp2 partials (no C output at all)
__global__ __launch_bounds__(256, 4)
void gemm_gelu_kernel(const unsigned short* __restrict__ A,
                      const unsigned short* __restrict__ Bt,
                      const float* __restrict__ bias,
                      const float* __restrict__ W2,
                      float* __restrict__ part) {
    __shared__ unsigned short As[2 * 4096];
    __shared__ unsigned short Bs[2 * 4096];
    gemm_body<768, 1, 392>(blockIdx.x, A, Bt, bias, nullptr, W2, part, As, Bs);
}

// ---------------- final reduce: 24 partials/row -> logits; rel fill --------
__global__ __launch_bounds__(256)
void mlp2_reduce_kernel(const float* __restrict__ part,
                        const float* __restrict__ b2,
                        float* __restrict__ out) {
    int row = blockIdx.x * 256 + threadIdx.x;   // 196 blocks x 256 = 50176
    const float4* p = (const float4*)(part + (size_t)row * 24);
    float a0 = 0.f, a1 = 0.f;
    #pragma unroll
    for (int i = 0; i < 6; ++i) {
        float4 v = p[i];
        a0 += v.x + v.z;
        a1 += v.y + v.w;
    }
    out[row * 2]      = a0 + b2[0];
    out[row * 2 + 1]  = a1 + b2[1];
    // rel_BN: softmax rows sum to 1 -> mean over Lt = 1/32, mean over H = 1/32
    out[100352 + row] = 0.03125f;
}

// ---------------- MFMA attention: one block per (b,h), 4 waves -------------
__global__ __launch_bounds__(256, 4)
void attn_mfma_kernel(const unsigned short* __restrict__ Q,
                      const unsigned short* __restrict__ Kb,
                      const unsigned short* __restrict__ Vb,
                      unsigned short* __restrict__ RF) {
    constexpr int KS = 72;  // Ks row stride
    constexpr int VS = 34;  // Vt row stride
    constexpr int PS = 40;  // P row stride
    constexpr int CS = 72;  // ctx row stride
    __shared__ unsigned short Ks[32 * KS];      // K rows  [l][d]
    __shared__ unsigned short Vt[64 * VS];      // V^T     [d][l]
    __shared__ unsigned short Pb[4][16 * PS];   // per-wave P  [m][l]
    __shared__ unsigned short Cb[4][16 * CS];   // per-wave ctx[m][d]
    const int tid = threadIdx.x;
    const int b = blockIdx.x / 12, h = blockIdx.x % 12;
    const int lane = tid & 63, wave = tid >> 6;
    const int lr = lane & 15, quad = lane >> 4;

    {   // stage K rows + V transposed (bf16, one-time)
        int l = tid >> 3, d8 = (tid & 7) * 8;
        size_t base = ((size_t)b * 32 + l) * 768 + (size_t)h * 64 + d8;
        bf16x8 kv = *(const bf16x8*)(Kb + base);
        bf16x8 vv = *(const bf16x8*)(Vb + base);
        *(bf16x8*)(Ks + l * KS + d8) = kv;
        #pragma unroll
        for (int j = 0; j < 8; ++j)
            Vt[(d8 + j) * VS + l] = (unsigned short)vv[j];
    }
    __syncthreads();

    bf16x8 fbK[2][2];
    #pragma unroll
    for (int n = 0; n < 2; ++n)
        #pragma unroll
        for (int ks = 0; ks < 2; ++ks)
            fbK[n][ks] = *(const bf16x8*)(Ks + (n * 16 + lr) * KS + ks * 32 + quad * 8);
    bf16x8 fbV[4];
    #pragma unroll
    for (int d = 0; d < 4; ++d)
        fbV[d] = *(const bf16x8*)(Vt + (d * 16 + lr) * VS + quad * 8);

    const size_t qbase = (size_t)b * 196 * 768 + (size_t)h * 64;

    for (int t = wave; t < 13; t += 4) {   // 13 tiles of 16 rows cover 196
        const int m0 = t * 16;
        int qrow = m0 + lr; if (qrow > 195) qrow = 195;  // clamp tail dups
        const unsigned short* qp = Q + qbase + (size_t)qrow * 768;
        bf16x8 fa0 = *(const bf16x8*)(qp + quad * 8);
        bf16x8 fa1 = *(const bf16x8*)(qp + 32 + quad * 8);

        // T14 issue-early: prefetch residual rows now, consumed at tile end.
        bf16x8 rv[2]; int rrow[2];
        #pragma unroll
        for (int i = 0; i < 2; ++i) {
            int c2 = lane + i * 64;
            rrow[i] = m0 + (c2 >> 3);
            if (rrow[i] < 196)
                rv[i] = *(const bf16x8*)(RF + qbase + (size_t)rrow[i] * 768 +
                                         (c2 & 7) * 8);
        }

        f32x4 s0 = {}, s1 = {};
        s0 = __builtin_amdgcn_mfma_f32_16x16x32_bf16(fa0, fbK[0][0], s0, 0, 0, 0);
        s0 = __builtin_amdgcn_mfma_f32_16x16x32_bf16(fa1, fbK[0][1], s0, 0, 0, 0);
        s1 = __builtin_amdgcn_mfma_f32_16x16x32_bf16(fa0, fbK[1][0], s1, 0, 0, 0);
        s1 = __builtin_amdgcn_mfma_f32_16x16x32_bf16(fa1, fbK[1][1], s1, 0, 0, 0);

        float p0[4], p1[4], m4[4], s4[4];
        #pragma unroll
        for (int r = 0; r < 4; ++r) {
            p0[r] = s0[r] * 0.125f;
            p1[r] = s1[r] * 0.125f;
            m4[r] = fmaxf(p0[r], p1[r]);
        }
        #pragma unroll
        for (int off = 1; off < 16; off <<= 1)
            #pragma unroll
            for (int r = 0; r < 4; ++r)
                m4[r] = fmaxf(m4[r], __shfl_xor(m4[r], off));
        #pragma unroll
        for (int r = 0; r < 4; ++r) {
            p0[r] = __expf(p0[r] - m4[r]);
            p1[r] = __expf(p1[r] - m4[r]);
            s4[r] = p0[r] + p1[r];
        }
        #pragma unroll
        for (int off = 1; off < 16; off <<= 1)
            #pragma unroll
            for (int r = 0; r < 4; ++r)
                s4[r] += __shfl_xor(s4[r], off);
        #pragma unroll
        for (int r = 0; r < 4; ++r) {
            float inv = __builtin_amdgcn_rcpf(s4[r]);
            unsigned short* pr = &Pb[wave][(quad * 4 + r) * PS];
            pr[lr]      = f2bf(p0[r] * inv);
            pr[16 + lr] = f2bf(p1[r] * inv);
        }

        bf16x8 fap = *(const bf16x8*)(&Pb[wave][lr * PS + quad * 8]);
        f32x4 c[4];
        #pragma unroll
        for (int d = 0; d < 4; ++d) {
            f32x4 z = {};
            c[d] = __builtin_amdgcn_mfma_f32_16x16x32_bf16(fap, fbV[d], z, 0, 0, 0);
        }
        #pragma unroll
        for (int d = 0; d < 4; ++d)
            #pragma unroll
            for (int r = 0; r < 4; ++r)
                Cb[wave][(quad * 4 + r) * CS + d * 16 + lr] = f2bf(c[d][r]);
        #pragma unroll
        for (int i = 0; i < 2; ++i) {
            int c2 = lane + i * 64;
            int row = c2 >> 3, col8 = (c2 & 7) * 8;
            if (rrow[i] < 196) {
                bf16x8 cv = *(const bf16x8*)(&Cb[wave][row * CS + col8]);
                unsigned short* gp = RF + qbase + (size_t)rrow[i] * 768 + col8;
                bf16x8 ov;
                #pragma unroll
                for (int j = 0; j < 8; ++j)
                    ov[j] = (short)f2bf(bf2f((unsigned short)cv[j]) +
                                        bf2f((unsigned short)rv[i][j]));
                *(bf16x8*)gp = ov;
            }
        }
    }
}

extern "C" void kernel_launch(void* const* d_in, const int* in_sizes, int n_in,
                              void* d_out, int out_size, void* d_ws, size_t ws_size,
                              hipStream_t stream) {
    const float* vis = (const float*)d_in[0];
    const float* txt = (const float*)d_in[1];
    const float* Wq  = (const float*)d_in[2];
    const float* bq  = (const float*)d_in[3];
    const float* Wk  = (const float*)d_in[4];
    const float* bk  = (const float*)d_in[5];
    const float* Wv  = (const float*)d_in[6];
    const float* bv  = (const float*)d_in[7];
    const float* W1  = (const float*)d_in[8];
    const float* b1  = (const float*)d_in[9];
    const float* W2  = (const float*)d_in[10];
    const float* b2  = (const float*)d_in[11];
    float* out = (float*)d_out;

    char* w = (char*)d_ws;
    unsigned short* Abf = (unsigned short*)(w);              // 77,070,336 B (vis bf16; becomes "fused")
    unsigned short* Tbf = (unsigned short*)(w + 77070336);   //  8,388,608 B (text bf16)
    unsigned short* Wqt = (unsigned short*)(w + 85458944);   //  1,179,648 B
    unsigned short* Wkt = (unsigned short*)(w + 86638592);   //    786,432 B
    unsigned short* Wvt = (unsigned short*)(w + 87425024);   //    786,432 B
    unsigned short* W1t = (unsigned short*)(w + 88211456);   //  1,179,648 B
    unsigned short* Qbf = (unsigned short*)(w + 89391104);   // 77,070,336 B
    unsigned short* Kbf = (unsigned short*)(w + 166461440);  // 12,582,912 B
    unsigned short* Vbf = (unsigned short*)(w + 179044352);  // 12,582,912 B
    // mlp2 partials: 50176 rows x 24 f32 = 4,816,896 B.
    // Reuses Kbf's region -- K is dead once attn completes, and the GELU
    // GEMM (producer) + reduce (consumer) both run after attn.
    float* Part = (float*)(w + 166461440);

    // 9,633,792 + 1,048,576 float4s = 41,728 blocks exactly
    cvt2_kernel<<<41728, 256, 0, stream>>>(vis, Abf, 9633792, txt, Tbf);
    transpose4_kernel<<<1920, 256, 0, stream>>>(Wq, Wqt, Wk, Wkt, Wv, Wvt,
                                                W1, W1t);

    gemm_qkv_kernel<<<3120, 256, 0, stream>>>(Abf, Wqt, bq, Qbf,
                                              Tbf, Wkt, bk, Kbf,
                                              Wvt, bv, Vbf);

    attn_mfma_kernel<<<3072, 256, 0, stream>>>(Qbf, Kbf, Vbf, Abf);

    // GELU GEMM writes race-free mlp2 partials into Part (ex-Kbf region)
    gemm_gelu_kernel<<<2352, 256, 0, stream>>>(Abf, W1t, b1, W2, Part);

    mlp2_reduce_kernel<<<196, 256, 0, stream>>>(Part, b2, out);
}